// Round 2
// baseline (1047.787 us; speedup 1.0000x reference)
//
#include <hip/hip_runtime.h>

typedef unsigned short ushort_t;
typedef unsigned int uint32;
typedef __attribute__((ext_vector_type(8))) short short8;
typedef __attribute__((ext_vector_type(4))) short short4v;
typedef __attribute__((ext_vector_type(4))) float floatx4;
typedef __attribute__((ext_vector_type(2))) float float2v;
typedef __attribute__((ext_vector_type(8))) int intx8;

#define B_    128
#define T_    512
#define H_    256
#define H2_   512
#define LIN_  200
#define LINP_ 224
#define G4_   1024
#define SP_   58
#define BT_   (B_*T_)

// ---------- ws layout (bytes) ----------
#define OFF_LS     0UL          // int  [B,T]      262144
#define OFF_LP     262144UL     // int  [B,T]      262144
#define OFF_WID    524288UL     // int  [B,T]      262144
#define OFF_INV    786432UL     // f32  [B,T]      262144
#define OFF_POSW   1212416UL    // f32  [32][200]   25600
#define OFF_WLW    1238016UL    // f32  [8][200]     6400
#define OFF_BIASG  1244416UL    // f32  [1024]       4096
#define OFF_WHH    1248512UL    // fp8  [1024][256] 262144
#define OFF_WIH    1772800UL    // bf16 [1024][224] 458752
#define OFF_WENC   2231552UL    // bf16 [200][512]  204800
#define OFF_COMBW  2436352UL    // bf16 [58][768]    89088
#define OFF_ECW    2525440UL    // bf16 [65536][200] time-major rows (t*128+b)
#define OFF_Z      28739840UL   // bf16 [65536][224] time-major rows
#define OFF_GPERM  58099968UL   // bf16 swizzled [512][32 blk][16 w][4 g][16 u][4 qd]
#define OFF_VBF    192317696UL  // bf16 [65536][768] time-major rows (0:256 hs, 256:768 enc)

__device__ __forceinline__ ushort_t f2bf(float x){
  uint32 u = __float_as_uint(x);
  u += 0x7fffu + ((u >> 16) & 1u);
  return (ushort_t)(u >> 16);
}
__device__ __forceinline__ float bf2f(ushort_t v){
  return __uint_as_float(((uint32)v) << 16);
}
// fast sigmoid/tanh (exp2-based __expf + v_rcp); |err| ~1e-5, way inside bf16
__device__ __forceinline__ float fsig(float x){
  return __builtin_amdgcn_rcpf(1.0f + __expf(-x));
}
__device__ __forceinline__ float ftanh(float x){
  return 1.0f - 2.0f * __builtin_amdgcn_rcpf(1.0f + __expf(2.0f * x));
}

// ---------- scan: last_sep / wordlen / last_pos (b-major aux arrays) ----------
__global__ void k_scan(const int* __restrict__ sep, const int* __restrict__ pos_ids,
                       int* __restrict__ ls, int* __restrict__ lp,
                       int* __restrict__ wid, float* __restrict__ inv){
  int b = blockIdx.x * 64 + threadIdx.x;
  if (b >= B_) return;
  int run = 0;
  for (int t = 0; t < T_; t++){
    int l = (t == 0) ? 0 : run;
    if (sep[b*T_ + t] > 0) run = t;
    int wlen = t - l;
    int wsv  = (wlen < 1) ? 1 : wlen;
    ls[b*T_ + t]  = l;
    lp[b*T_ + t]  = pos_ids[b*T_ + l];
    wid[b*T_ + t] = (wsv > 7) ? 7 : wsv;
    inv[b*T_ + t] = 1.0f / (float)wsv;
  }
}

// ---------- enc -> bf16 into vbf[t*128+b][256:768] ----------
__global__ __launch_bounds__(256) void k_encbf(const float* __restrict__ enc, ushort_t* __restrict__ vbf){
  long row = blockIdx.x;           // b*512 + t (matches enc layout)
  int b = (int)(row >> 9), t = (int)(row & (T_-1));
  int c = threadIdx.x;
  const float* e = enc + row * H2_;
  ushort_t* v = vbf + ((long)t * B_ + b) * 768 + 256;
  v[c]       = f2bf(e[c]);
  v[c + 256] = f2bf(e[c + 256]);
}

// ---------- small precomputes / weight conversions ----------
__global__ __launch_bounds__(256) void k_small(
    const float* __restrict__ pos_emb, const float* __restrict__ wl_emb,
    const float* __restrict__ fcW, const float* __restrict__ W_ih,
    const float* __restrict__ W_hh, const float* __restrict__ b_ih,
    const float* __restrict__ b_hh, const float* __restrict__ combW,
    float* __restrict__ posW, float* __restrict__ wlW, float* __restrict__ biasg,
    char* __restrict__ whh8, ushort_t* __restrict__ wih,
    ushort_t* __restrict__ wenc, ushort_t* __restrict__ combwb){
  int idx = blockIdx.x * 256 + threadIdx.x;
  if (idx < 6400){
    int p = idx / 200, l = idx % 200;
    float s = 0.f;
    for (int d = 0; d < 50; d++) s += pos_emb[p*50 + d] * fcW[l*582 + d];
    posW[idx] = s; return;
  }
  idx -= 6400;
  if (idx < 1600){
    int w = idx / 200, l = idx % 200;
    float s = 0.f;
    for (int d = 0; d < 20; d++) s += wl_emb[w*20 + d] * fcW[l*582 + 562 + d];
    wlW[idx] = s; return;
  }
  idx -= 1600;
  if (idx < 1024){ biasg[idx] = b_ih[idx] + b_hh[idx]; return; }
  idx -= 1024;
  if (idx < 262144){
    int p8 = __builtin_amdgcn_cvt_pk_fp8_f32(W_hh[idx], W_hh[idx], 0, false);
    whh8[idx] = (char)(p8 & 0xff);
    return;
  }
  idx -= 262144;
  if (idx < 229376){
    int n = idx / 224, k = idx % 224;
    wih[idx] = (k < 200) ? f2bf(W_ih[n*200 + k]) : (ushort_t)0;
    return;
  }
  idx -= 229376;
  if (idx < 102400){
    int l = idx / 512, c = idx % 512;
    wenc[idx] = f2bf(fcW[l*582 + 50 + c]); return;
  }
  idx -= 102400;
  if (idx < 44544){ combwb[idx] = f2bf(combW[idx]); return; }
}

// ---------- generic 64x64 bf16 MFMA GEMM: C[m,n] = sum_k A[m,k]*B[n,k] ----------
// EPI 0: bf16 out [m][Nvalid]
// EPI 1: +bias, bf16 out in k_rec Gperm layout [t][blk32][w16][g4][u16][qd4]
// EPI 2: masked fp32 logits, m time-major -> out b-major [b*T+t][58]
template<int EPI>
__global__ __launch_bounds__(256) void k_gemm(
    const ushort_t* __restrict__ A, long lda,
    const ushort_t* __restrict__ Bm, int K, int Nvalid,
    void* __restrict__ Cout, const float* __restrict__ bias, const int* __restrict__ len){
  __shared__ __attribute__((aligned(16))) ushort_t As[64][48];
  __shared__ __attribute__((aligned(16))) ushort_t Bs[64][48];
  int tid  = threadIdx.x;
  int lane = tid & 63, wave = tid >> 6;
  int u = lane & 15, quad = lane >> 4;
  int mh = wave >> 1, nh = wave & 1;
  long m0 = (long)blockIdx.x * 64;
  int  n0 = blockIdx.y * 64;
  int lrow = tid >> 2;
  int lcol = (tid & 3) * 8;
  const ushort_t* Arow = A + (m0 + lrow) * lda + lcol;
  bool bvalid = (n0 + lrow) < Nvalid;
  const ushort_t* Brow = Bm + (long)(n0 + lrow) * K + lcol;
  floatx4 acc[2][2] = {};
  for (int k = 0; k < K; k += 32){
    short8 av = *(const short8*)(const void*)(Arow + k);
    short8 bv = {0,0,0,0,0,0,0,0};
    if (bvalid) bv = *(const short8*)(const void*)(Brow + k);
    __syncthreads();
    *(short8*)(void*)&As[lrow][lcol] = av;
    *(short8*)(void*)&Bs[lrow][lcol] = bv;
    __syncthreads();
    short8 a0 = *(const short8*)(const void*)&As[mh*32 + u][quad*8];
    short8 a1 = *(const short8*)(const void*)&As[mh*32 + 16 + u][quad*8];
    short8 b0 = *(const short8*)(const void*)&Bs[nh*32 + u][quad*8];
    short8 b1 = *(const short8*)(const void*)&Bs[nh*32 + 16 + u][quad*8];
    acc[0][0] = __builtin_amdgcn_mfma_f32_16x16x32_bf16(a0, b0, acc[0][0], 0, 0, 0);
    acc[0][1] = __builtin_amdgcn_mfma_f32_16x16x32_bf16(a0, b1, acc[0][1], 0, 0, 0);
    acc[1][0] = __builtin_amdgcn_mfma_f32_16x16x32_bf16(a1, b0, acc[1][0], 0, 0, 0);
    acc[1][1] = __builtin_amdgcn_mfma_f32_16x16x32_bf16(a1, b1, acc[1][1], 0, 0, 0);
  }
  if (EPI == 1){
    #pragma unroll
    for (int mi = 0; mi < 2; mi++){
      #pragma unroll
      for (int ni = 0; ni < 2; ni++){
        long mm = m0 + mh*32 + mi*16 + quad*4;     // 4 r's = 4 consecutive b (qd 0..3)
        int n = n0 + nh*32 + ni*16 + u;
        float bv = bias[n];
        int t = (int)(mm >> 7);
        int b = (int)(mm & 127);
        int blk = b >> 2;                           // b % 4 == 0 here
        int g = n >> 8, j = n & 255, ut = j & 15, jt = j >> 4;
        long idx = ((((long)t*32 + blk)*16 + jt)*4 + g)*64 + ut*4;
        short4v pk;
        #pragma unroll
        for (int r = 0; r < 4; r++) pk[r] = (short)f2bf(acc[mi][ni][r] + bv);
        *(short4v*)(void*)((ushort_t*)Cout + idx) = pk;
      }
    }
  } else {
    for (int mi = 0; mi < 2; mi++){
      for (int ni = 0; ni < 2; ni++){
        for (int r = 0; r < 4; r++){
          long m = m0 + mh*32 + mi*16 + quad*4 + r;
          int  n = n0 + nh*32 + ni*16 + u;
          float v = acc[mi][ni][r];
          if (EPI == 0){
            if (n < Nvalid) ((ushort_t*)Cout)[m * Nvalid + n] = f2bf(v);
          } else {
            if (n < Nvalid){
              int t = (int)(m >> 7); int b = (int)(m & 127);
              float o = (t < len[b]) ? v : 0.0f;
              if (t == 0 && n == 0) o = -1e30f;
              ((float*)Cout)[((long)b * T_ + t) * SP_ + n] = o;
            }
          }
        }
      }
    }
  }
}

// ---------- exclusive cumsum over t, in place on E (bf16, time-major rows) ----------
__global__ __launch_bounds__(256) void k_cum200(ushort_t* __restrict__ E){
  int b = blockIdx.x;
  int c = threadIdx.x;
  if (c >= LIN_) return;
  float acc = 0.f;
  ushort_t* p = E + (long)b * LIN_ + c;      // row (t*128+b)
  const long rs = (long)B_ * LIN_;           // per-t stride
  for (int t0 = 0; t0 < T_; t0 += 16){
    float vv[16];
    #pragma unroll
    for (int i = 0; i < 16; i++) vv[i] = bf2f(p[i*rs]);
    #pragma unroll
    for (int i = 0; i < 16; i++){ p[i*rs] = f2bf(acc); acc += vv[i]; }
    p += 16*rs;
  }
}

// ---------- z = tanh((CW[t]-CW[ls])*inv + posW + wlW + b), t=0 -> 0, pad K to 224 ----------
__global__ __launch_bounds__(256) void k_z(
    const ushort_t* __restrict__ CW, const int* __restrict__ ls, const int* __restrict__ lp,
    const int* __restrict__ wid, const float* __restrict__ inv,
    const float* __restrict__ posW, const float* __restrict__ wlW,
    const float* __restrict__ fcb, ushort_t* __restrict__ zbf){
  int m = blockIdx.x;               // time-major row t*128+b
  int l = threadIdx.x;
  if (l >= LINP_) return;
  int t = m >> 7;
  int b = m & 127;
  int ar = b * T_ + t;              // b-major aux index
  ushort_t o = 0;
  if (t != 0 && l < LIN_){
    int lsv = ls[ar];
    float x = bf2f(CW[(long)m * LIN_ + l]) - bf2f(CW[((long)lsv * B_ + b) * LIN_ + l]);
    x = x * inv[ar] + posW[lp[ar]*LIN_ + l] + wlW[wid[ar]*LIN_ + l] + fcb[l];
    o = f2bf(ftanh(x));
  }
  zbf[(long)m * LINP_ + l] = o;
}

// ---------- LSTM recurrence: 32 blocks x 1024 threads, NB=4 batches/block ----------
// h kept in 4 PACKED LDS rows (h4[buf][batch][272]); A-rows u%4!=0 are zero and are
// materialized as constant-zero VGPRs under exec mask instead of being read from LDS
// (the old [16]-row layout spent 75% of the 64KB/step LDS read traffic on zeros and
// 256 conflict-cyc/step). Reads now: 16 active lanes x b128, 2-way banks (free).
__global__ __launch_bounds__(1024, 4) void k_rec(
    const ushort_t* __restrict__ Gperm, const char* __restrict__ whh8,
    ushort_t* __restrict__ vbf){
  int blk  = blockIdx.x;                      // 0..31: batches blk*4 .. blk*4+3
  int tid  = threadIdx.x;
  int lane = tid & 63, w = tid >> 6;          // w in [0,16): hidden j-tile
  int u = lane & 15, quad = lane >> 4;        // quad = local batch index
  __shared__ __attribute__((aligned(16))) char h4[2][4][272];   // packed batch rows
  for (int i = tid; i < (int)(sizeof(h4)/4); i += 1024) ((int*)h4)[i] = 0;

  // W_hh fp8 B-fragments (MX K=128): gate g, cols w*16+u; pinned in VGPRs.
  intx8 wfx[4][2];
  #pragma unroll
  for (int g = 0; g < 4; g++){
    int grow = g*256 + w*16 + u;
    #pragma unroll
    for (int kc = 0; kc < 2; kc++){
      intx8 v = *(const intx8*)(const void*)(whh8 + (long)grow*256 + kc*128 + quad*32);
      asm volatile("" : "+v"(v));
      wfx[g][kc] = v;
    }
  }
  float c_reg = 0.f;
  floatx4 acc[4] = {};   // element 0 rebuilt each step; elements 1..3 stay 0 forever
  bool arow = ((u & 3) == 0);                 // this lane's A-row is a real batch
  int  abat = u >> 2;                         // which batch row it reads

  // Gperm[t][blk][w][g][u][qd]: lane (quad,u) reads gate g at g*64 + u*4 + quad
  const ushort_t* gp0 = Gperm + ((long)blk*16 + w)*256 + (long)u*4 + quad;
  ushort_t gb[4];
  #pragma unroll
  for (int g = 0; g < 4; g++) gb[g] = gp0[g*64];

  for (int t = 0; t < T_; t++){
    #pragma unroll
    for (int g = 0; g < 4; g++) acc[g][0] = bf2f(gb[g]);
    __syncthreads();                       // h4[t&1] = h(t-1) ready
    intx8 af0 = {0,0,0,0,0,0,0,0};
    intx8 af1 = {0,0,0,0,0,0,0,0};
    if (arow){
      const char* hb = &h4[t & 1][abat][quad*32];
      af0 = *(const intx8*)(const void*)hb;
      af1 = *(const intx8*)(const void*)(hb + 128);
    }
    #pragma unroll
    for (int g = 0; g < 4; g++){
      acc[g] = __builtin_amdgcn_mfma_scale_f32_16x16x128_f8f6f4(
          af0, wfx[g][0], acc[g], 0, 0, 0, 0x7F7F7F7F, 0, 0x7F7F7F7F);
      acc[g] = __builtin_amdgcn_mfma_scale_f32_16x16x128_f8f6f4(
          af1, wfx[g][1], acc[g], 0, 0, 0, 0x7F7F7F7F, 0, 0x7F7F7F7F);
    }
    // coalesced vbf dump of h(t-1): waves 0..3 own batch rows 0..3
    if (t && w < 4){
      ushort_t* vrow = vbf + ((long)(t-1) * B_ + blk*4 + w) * 768;
      uint32 p = *(const uint32*)(const void*)&h4[t & 1][w][lane*4];
      float2v lo = __builtin_amdgcn_cvt_pk_f32_fp8(p, false);
      float2v hi = __builtin_amdgcn_cvt_pk_f32_fp8(p, true);
      short4v pk;
      pk[0] = (short)f2bf(lo[0]); pk[1] = (short)f2bf(lo[1]);
      pk[2] = (short)f2bf(hi[0]); pk[3] = (short)f2bf(hi[1]);
      *(short4v*)(void*)&vrow[lane*4] = pk;
    }
    // prefetch next Gperm values (4 coalesced ushort loads, 128B dense per inst)
    if (t + 1 < T_){
      const ushort_t* gp = gp0 + (long)(t+1)*131072;
      #pragma unroll
      for (int g = 0; g < 4; g++) gb[g] = gp[g*64];
    }
    // epilogue: single row r=0; lane (quad,u) = batch blk*4+quad, j = w*16+u
    {
      float iv = fsig (acc[0][0]);
      float fv = fsig (acc[1][0]);
      float gv = ftanh(acc[2][0]);
      float ov = fsig (acc[3][0]);
      float c  = fv * c_reg + iv * gv;
      c_reg = c;
      float h  = ov * ftanh(c);
      int p8 = __builtin_amdgcn_cvt_pk_fp8_f32(h, h, 0, false);
      h4[(t+1)&1][quad][w*16 + u] = (char)(p8 & 0xff);
    }
  }
  __syncthreads();
  // final dump: h(511) lives in h4[0]
  if (w < 4){
    ushort_t* vrow = vbf + ((long)(T_-1) * B_ + blk*4 + w) * 768;
    uint32 p = *(const uint32*)(const void*)&h4[0][w][lane*4];
    float2v lo = __builtin_amdgcn_cvt_pk_f32_fp8(p, false);
    float2v hi = __builtin_amdgcn_cvt_pk_f32_fp8(p, true);
    short4v pk;
    pk[0] = (short)f2bf(lo[0]); pk[1] = (short)f2bf(lo[1]);
    pk[2] = (short)f2bf(hi[0]); pk[3] = (short)f2bf(hi[1]);
    *(short4v*)(void*)&vrow[lane*4] = pk;
  }
}

extern "C" void kernel_launch(void* const* d_in, const int* in_sizes, int n_in,
                              void* d_out, int out_size, void* d_ws, size_t ws_size,
                              hipStream_t stream){
  (void)in_sizes; (void)n_in; (void)out_size; (void)ws_size;
  const float* enc     = (const float*)d_in[0];
  const int*   sep     = (const int*)  d_in[1];
  const int*   pos_ids = (const int*)  d_in[2];
  const int*   len     = (const int*)  d_in[3];
  const float* pos_emb = (const float*)d_in[4];
  const float* wl_emb  = (const float*)d_in[5];
  const float* fcW     = (const float*)d_in[6];
  const float* fcb     = (const float*)d_in[7];
  const float* W_ih    = (const float*)d_in[8];
  const float* W_hh    = (const float*)d_in[9];
  const float* b_ih    = (const float*)d_in[10];
  const float* b_hh    = (const float*)d_in[11];
  const float* combW   = (const float*)d_in[12];

  char* ws = (char*)d_ws;
  int*      ls    = (int*)     (ws + OFF_LS);
  int*      lp    = (int*)     (ws + OFF_LP);
  int*      wid   = (int*)     (ws + OFF_WID);
  float*    inv   = (float*)   (ws + OFF_INV);
  float*    posW  = (float*)   (ws + OFF_POSW);
  float*    wlW   = (float*)   (ws + OFF_WLW);
  float*    biasg = (float*)   (ws + OFF_BIASG);
  char*     whh8  = (char*)    (ws + OFF_WHH);
  ushort_t* wih   = (ushort_t*)(ws + OFF_WIH);
  ushort_t* wenc  = (ushort_t*)(ws + OFF_WENC);
  ushort_t* combwb= (ushort_t*)(ws + OFF_COMBW);
  ushort_t* ecw   = (ushort_t*)(ws + OFF_ECW);
  ushort_t* zbf   = (ushort_t*)(ws + OFF_Z);
  ushort_t* gperm = (ushort_t*)(ws + OFF_GPERM);
  ushort_t* vbf   = (ushort_t*)(ws + OFF_VBF);

  k_scan<<<2, 64, 0, stream>>>(sep, pos_ids, ls, lp, wid, inv);
  k_encbf<<<BT_, 256, 0, stream>>>(enc, vbf);
  k_small<<<2530, 256, 0, stream>>>(pos_emb, wl_emb, fcW, W_ih, W_hh, b_ih, b_hh, combW,
                                    posW, wlW, biasg, whh8, wih, wenc, combwb);
  // E = enc @ Wenc^T  (rows time-major)
  k_gemm<0><<<dim3(BT_/64, 4), 256, 0, stream>>>(vbf + 256, 768L, wenc, 512, LIN_, ecw, nullptr, nullptr);
  // exclusive cumsum over t (in place) -> CW
  k_cum200<<<B_, 256, 0, stream>>>(ecw);
  // z = tanh(...)
  k_z<<<BT_, 256, 0, stream>>>(ecw, ls, lp, wid, inv, posW, wlW, fcb, zbf);
  // Gperm = z @ W_ih^T + biases, written in k_rec's [t][blk][w][g][u][qd] layout
  k_gemm<1><<<dim3(BT_/64, 16), 256, 0, stream>>>(zbf, (long)LINP_, wih, LINP_, G4_, gperm, biasg, nullptr);
  // LSTM recurrence (32 blocks x 16 waves, packed-h4 zero-skip A reads)
  k_rec<<<32, 1024, 0, stream>>>(gperm, whh8, vbf);
  // logits = [hs, enc] @ combine_W^T, masked, scattered to b-major output
  k_gemm<2><<<dim3(BT_/64, 1), 256, 0, stream>>>(vbf, 768L, combwb, 768, SP_, d_out, nullptr, len);
}

// Round 3
// 1023.147 us; speedup vs baseline: 1.0241x; 1.0241x over previous
//
#include <hip/hip_runtime.h>

typedef unsigned short ushort_t;
typedef unsigned int uint32;
typedef __attribute__((ext_vector_type(8))) short short8;
typedef __attribute__((ext_vector_type(4))) short short4v;
typedef __attribute__((ext_vector_type(4))) float floatx4;
typedef __attribute__((ext_vector_type(2))) float float2v;
typedef __attribute__((ext_vector_type(8))) int intx8;

#define B_    128
#define T_    512
#define H_    256
#define H2_   512
#define LIN_  200
#define LINP_ 224
#define G4_   1024
#define SP_   58
#define BT_   (B_*T_)

// ---------- ws layout (bytes) ----------
#define OFF_LS     0UL          // int  [B,T]      262144
#define OFF_LP     262144UL     // int  [B,T]      262144
#define OFF_WID    524288UL     // int  [B,T]      262144
#define OFF_INV    786432UL     // f32  [B,T]      262144
#define OFF_POSW   1212416UL    // f32  [32][200]   25600
#define OFF_WLW    1238016UL    // f32  [8][200]     6400
#define OFF_BIASG  1244416UL    // f32  [1024]       4096
#define OFF_WHH    1248512UL    // fp8  [1024][256] 262144
#define OFF_WIH    1772800UL    // bf16 [1024][224] 458752
#define OFF_WENC   2231552UL    // bf16 [200][512]  204800
#define OFF_COMBW  2436352UL    // bf16 [58][768]    89088
#define OFF_ECW    2525440UL    // bf16 [65536][200] time-major rows (t*128+b)
#define OFF_Z      28739840UL   // bf16 [65536][224] time-major rows
#define OFF_GPERM  58099968UL   // bf16 swizzled [512][32 blk][16 w][4 g][16 u][4 qd]
#define OFF_VBF    192317696UL  // bf16 [65536][768] time-major rows (0:256 hs, 256:768 enc)

__device__ __forceinline__ ushort_t f2bf(float x){
  uint32 u = __float_as_uint(x);
  u += 0x7fffu + ((u >> 16) & 1u);
  return (ushort_t)(u >> 16);
}
__device__ __forceinline__ float bf2f(ushort_t v){
  return __uint_as_float(((uint32)v) << 16);
}
// fast sigmoid/tanh (exp2-based __expf + v_rcp); |err| ~1e-5, way inside bf16
__device__ __forceinline__ float fsig(float x){
  return __builtin_amdgcn_rcpf(1.0f + __expf(-x));
}
__device__ __forceinline__ float ftanh(float x){
  return 1.0f - 2.0f * __builtin_amdgcn_rcpf(1.0f + __expf(2.0f * x));
}

// ---------- scan: last_sep / wordlen / last_pos (b-major aux arrays) ----------
__global__ void k_scan(const int* __restrict__ sep, const int* __restrict__ pos_ids,
                       int* __restrict__ ls, int* __restrict__ lp,
                       int* __restrict__ wid, float* __restrict__ inv){
  int b = blockIdx.x * 64 + threadIdx.x;
  if (b >= B_) return;
  int run = 0;
  for (int t = 0; t < T_; t++){
    int l = (t == 0) ? 0 : run;
    if (sep[b*T_ + t] > 0) run = t;
    int wlen = t - l;
    int wsv  = (wlen < 1) ? 1 : wlen;
    ls[b*T_ + t]  = l;
    lp[b*T_ + t]  = pos_ids[b*T_ + l];
    wid[b*T_ + t] = (wsv > 7) ? 7 : wsv;
    inv[b*T_ + t] = 1.0f / (float)wsv;
  }
}

// ---------- enc -> bf16 into vbf[t*128+b][256:768] ----------
__global__ __launch_bounds__(256) void k_encbf(const float* __restrict__ enc, ushort_t* __restrict__ vbf){
  long row = blockIdx.x;           // b*512 + t (matches enc layout)
  int b = (int)(row >> 9), t = (int)(row & (T_-1));
  int c = threadIdx.x;
  const float* e = enc + row * H2_;
  ushort_t* v = vbf + ((long)t * B_ + b) * 768 + 256;
  v[c]       = f2bf(e[c]);
  v[c + 256] = f2bf(e[c + 256]);
}

// ---------- small precomputes / weight conversions ----------
__global__ __launch_bounds__(256) void k_small(
    const float* __restrict__ pos_emb, const float* __restrict__ wl_emb,
    const float* __restrict__ fcW, const float* __restrict__ W_ih,
    const float* __restrict__ W_hh, const float* __restrict__ b_ih,
    const float* __restrict__ b_hh, const float* __restrict__ combW,
    float* __restrict__ posW, float* __restrict__ wlW, float* __restrict__ biasg,
    char* __restrict__ whh8, ushort_t* __restrict__ wih,
    ushort_t* __restrict__ wenc, ushort_t* __restrict__ combwb){
  int idx = blockIdx.x * 256 + threadIdx.x;
  if (idx < 6400){
    int p = idx / 200, l = idx % 200;
    float s = 0.f;
    for (int d = 0; d < 50; d++) s += pos_emb[p*50 + d] * fcW[l*582 + d];
    posW[idx] = s; return;
  }
  idx -= 6400;
  if (idx < 1600){
    int w = idx / 200, l = idx % 200;
    float s = 0.f;
    for (int d = 0; d < 20; d++) s += wl_emb[w*20 + d] * fcW[l*582 + 562 + d];
    wlW[idx] = s; return;
  }
  idx -= 1600;
  if (idx < 1024){ biasg[idx] = b_ih[idx] + b_hh[idx]; return; }
  idx -= 1024;
  if (idx < 262144){
    int p8 = __builtin_amdgcn_cvt_pk_fp8_f32(W_hh[idx], W_hh[idx], 0, false);
    whh8[idx] = (char)(p8 & 0xff);
    return;
  }
  idx -= 262144;
  if (idx < 229376){
    int n = idx / 224, k = idx % 224;
    wih[idx] = (k < 200) ? f2bf(W_ih[n*200 + k]) : (ushort_t)0;
    return;
  }
  idx -= 229376;
  if (idx < 102400){
    int l = idx / 512, c = idx % 512;
    wenc[idx] = f2bf(fcW[l*582 + 50 + c]); return;
  }
  idx -= 102400;
  if (idx < 44544){ combwb[idx] = f2bf(combW[idx]); return; }
}

// ---------- generic 64x64 bf16 MFMA GEMM: C[m,n] = sum_k A[m,k]*B[n,k] ----------
// Grid: x = N-tiles (FAST dim), y = M-blocks. Consecutive blocks share the same
// 64-row A panel -> A streamed from HBM once, re-reads served by L2/L3 (T1).
// EPI 0: bf16 out [m][Nvalid]
// EPI 1: +bias, bf16 out in k_rec Gperm layout [t][blk32][w16][g4][u16][qd4]
// EPI 2: masked fp32 logits, m time-major -> out b-major [b*T+t][58]
template<int EPI>
__global__ __launch_bounds__(256) void k_gemm(
    const ushort_t* __restrict__ A, long lda,
    const ushort_t* __restrict__ Bm, int K, int Nvalid,
    void* __restrict__ Cout, const float* __restrict__ bias, const int* __restrict__ len){
  __shared__ __attribute__((aligned(16))) ushort_t As[64][48];
  __shared__ __attribute__((aligned(16))) ushort_t Bs[64][48];
  int tid  = threadIdx.x;
  int lane = tid & 63, wave = tid >> 6;
  int u = lane & 15, quad = lane >> 4;
  int mh = wave >> 1, nh = wave & 1;
  long m0 = (long)blockIdx.y * 64;
  int  n0 = blockIdx.x * 64;
  int lrow = tid >> 2;
  int lcol = (tid & 3) * 8;
  const ushort_t* Arow = A + (m0 + lrow) * lda + lcol;
  bool bvalid = (n0 + lrow) < Nvalid;
  const ushort_t* Brow = Bm + (long)(n0 + lrow) * K + lcol;
  floatx4 acc[2][2] = {};
  for (int k = 0; k < K; k += 32){
    short8 av = *(const short8*)(const void*)(Arow + k);
    short8 bv = {0,0,0,0,0,0,0,0};
    if (bvalid) bv = *(const short8*)(const void*)(Brow + k);
    __syncthreads();
    *(short8*)(void*)&As[lrow][lcol] = av;
    *(short8*)(void*)&Bs[lrow][lcol] = bv;
    __syncthreads();
    short8 a0 = *(const short8*)(const void*)&As[mh*32 + u][quad*8];
    short8 a1 = *(const short8*)(const void*)&As[mh*32 + 16 + u][quad*8];
    short8 b0 = *(const short8*)(const void*)&Bs[nh*32 + u][quad*8];
    short8 b1 = *(const short8*)(const void*)&Bs[nh*32 + 16 + u][quad*8];
    acc[0][0] = __builtin_amdgcn_mfma_f32_16x16x32_bf16(a0, b0, acc[0][0], 0, 0, 0);
    acc[0][1] = __builtin_amdgcn_mfma_f32_16x16x32_bf16(a0, b1, acc[0][1], 0, 0, 0);
    acc[1][0] = __builtin_amdgcn_mfma_f32_16x16x32_bf16(a1, b0, acc[1][0], 0, 0, 0);
    acc[1][1] = __builtin_amdgcn_mfma_f32_16x16x32_bf16(a1, b1, acc[1][1], 0, 0, 0);
  }
  if (EPI == 1){
    #pragma unroll
    for (int mi = 0; mi < 2; mi++){
      #pragma unroll
      for (int ni = 0; ni < 2; ni++){
        long mm = m0 + mh*32 + mi*16 + quad*4;     // 4 r's = 4 consecutive b (qd 0..3)
        int n = n0 + nh*32 + ni*16 + u;
        float bv = bias[n];
        int t = (int)(mm >> 7);
        int b = (int)(mm & 127);
        int blk = b >> 2;                           // b % 4 == 0 here
        int g = n >> 8, j = n & 255, ut = j & 15, jt = j >> 4;
        long idx = ((((long)t*32 + blk)*16 + jt)*4 + g)*64 + ut*4;
        short4v pk;
        #pragma unroll
        for (int r = 0; r < 4; r++) pk[r] = (short)f2bf(acc[mi][ni][r] + bv);
        *(short4v*)(void*)((ushort_t*)Cout + idx) = pk;
      }
    }
  } else {
    for (int mi = 0; mi < 2; mi++){
      for (int ni = 0; ni < 2; ni++){
        for (int r = 0; r < 4; r++){
          long m = m0 + mh*32 + mi*16 + quad*4 + r;
          int  n = n0 + nh*32 + ni*16 + u;
          float v = acc[mi][ni][r];
          if (EPI == 0){
            if (n < Nvalid) ((ushort_t*)Cout)[m * Nvalid + n] = f2bf(v);
          } else {
            if (n < Nvalid){
              int t = (int)(m >> 7); int b = (int)(m & 127);
              float o = (t < len[b]) ? v : 0.0f;
              if (t == 0 && n == 0) o = -1e30f;
              ((float*)Cout)[((long)b * T_ + t) * SP_ + n] = o;
            }
          }
        }
      }
    }
  }
}

// ---------- exclusive cumsum over t, in place on E (bf16, time-major rows) ----------
__global__ __launch_bounds__(256) void k_cum200(ushort_t* __restrict__ E){
  int b = blockIdx.x;
  int c = threadIdx.x;
  if (c >= LIN_) return;
  float acc = 0.f;
  ushort_t* p = E + (long)b * LIN_ + c;      // row (t*128+b)
  const long rs = (long)B_ * LIN_;           // per-t stride
  for (int t0 = 0; t0 < T_; t0 += 16){
    float vv[16];
    #pragma unroll
    for (int i = 0; i < 16; i++) vv[i] = bf2f(p[i*rs]);
    #pragma unroll
    for (int i = 0; i < 16; i++){ p[i*rs] = f2bf(acc); acc += vv[i]; }
    p += 16*rs;
  }
}

// ---------- z = tanh((CW[t]-CW[ls])*inv + posW + wlW + b), t=0 -> 0, pad K to 224 ----------
__global__ __launch_bounds__(256) void k_z(
    const ushort_t* __restrict__ CW, const int* __restrict__ ls, const int* __restrict__ lp,
    const int* __restrict__ wid, const float* __restrict__ inv,
    const float* __restrict__ posW, const float* __restrict__ wlW,
    const float* __restrict__ fcb, ushort_t* __restrict__ zbf){
  int m = blockIdx.x;               // time-major row t*128+b
  int l = threadIdx.x;
  if (l >= LINP_) return;
  int t = m >> 7;
  int b = m & 127;
  int ar = b * T_ + t;              // b-major aux index
  ushort_t o = 0;
  if (t != 0 && l < LIN_){
    int lsv = ls[ar];
    float x = bf2f(CW[(long)m * LIN_ + l]) - bf2f(CW[((long)lsv * B_ + b) * LIN_ + l]);
    x = x * inv[ar] + posW[lp[ar]*LIN_ + l] + wlW[wid[ar]*LIN_ + l] + fcb[l];
    o = f2bf(ftanh(x));
  }
  zbf[(long)m * LINP_ + l] = o;
}

// ---------- LSTM recurrence: 32 blocks x 1024 threads, NB=4 batches/block ----------
// Batches placed at A-rows {0,4,8,12} -> C-row 4*quad at r=0: every lane owns exactly
// one (batch=blk*4+quad, j=w*16+u) output; epilogue is a single r-iteration with all
// 64 lanes active. acc rows r>0 are fed zero A-rows so they stay exactly 0.
// NOTE: packed-h4 + exec-masked A-read variant REGRESSED (501 vs 468 us; conflicts
// unchanged at 256/block/step, VALUBusy +1pt from per-step af zero-rematerialize) --
// LDS read volume is hidden under the MFMA pipe; keep full-lane reads.
__global__ __launch_bounds__(1024, 4) void k_rec(
    const ushort_t* __restrict__ Gperm, const char* __restrict__ whh8,
    ushort_t* __restrict__ vbf){
  int blk  = blockIdx.x;                      // 0..31: batches blk*4 .. blk*4+3
  int tid  = threadIdx.x;
  int lane = tid & 63, w = tid >> 6;          // w in [0,16): hidden j-tile
  int u = lane & 15, quad = lane >> 4;        // quad = local batch index
  __shared__ __attribute__((aligned(16))) char h8[2][16][272];   // row stride 272
  for (int i = tid; i < (int)(sizeof(h8)/4); i += 1024) ((int*)h8)[i] = 0;

  // W_hh fp8 B-fragments (MX K=128): gate g, cols w*16+u; pinned in VGPRs.
  intx8 wfx[4][2];
  #pragma unroll
  for (int g = 0; g < 4; g++){
    int grow = g*256 + w*16 + u;
    #pragma unroll
    for (int kc = 0; kc < 2; kc++){
      intx8 v = *(const intx8*)(const void*)(whh8 + (long)grow*256 + kc*128 + quad*32);
      asm volatile("" : "+v"(v));
      wfx[g][kc] = v;
    }
  }
  float c_reg = 0.f;
  floatx4 acc[4] = {};   // element 0 rebuilt each step; elements 1..3 stay 0 forever

  // Gperm[t][blk][w][g][u][qd]: lane (quad,u) reads gate g at g*64 + u*4 + quad
  const ushort_t* gp0 = Gperm + ((long)blk*16 + w)*256 + (long)u*4 + quad;
  ushort_t gb[4];
  #pragma unroll
  for (int g = 0; g < 4; g++) gb[g] = gp0[g*64];

  for (int t = 0; t < T_; t++){
    #pragma unroll
    for (int g = 0; g < 4; g++) acc[g][0] = bf2f(gb[g]);
    __syncthreads();                       // h8[t&1] = h(t-1) ready
    intx8 af0 = *(const intx8*)(const void*)&h8[t & 1][u][quad*32];
    intx8 af1 = *(const intx8*)(const void*)&h8[t & 1][u][128 + quad*32];
    #pragma unroll
    for (int g = 0; g < 4; g++){
      acc[g] = __builtin_amdgcn_mfma_scale_f32_16x16x128_f8f6f4(
          af0, wfx[g][0], acc[g], 0, 0, 0, 0x7F7F7F7F, 0, 0x7F7F7F7F);
      acc[g] = __builtin_amdgcn_mfma_scale_f32_16x16x128_f8f6f4(
          af1, wfx[g][1], acc[g], 0, 0, 0, 0x7F7F7F7F, 0, 0x7F7F7F7F);
    }
    // coalesced vbf dump of h(t-1): waves 0..3 own batch rows 0..3 (LDS rows 4*w)
    if (t && w < 4){
      ushort_t* vrow = vbf + ((long)(t-1) * B_ + blk*4 + w) * 768;
      uint32 p = *(const uint32*)(const void*)&h8[t & 1][4*w][lane*4];
      float2v lo = __builtin_amdgcn_cvt_pk_f32_fp8(p, false);
      float2v hi = __builtin_amdgcn_cvt_pk_f32_fp8(p, true);
      short4v pk;
      pk[0] = (short)f2bf(lo[0]); pk[1] = (short)f2bf(lo[1]);
      pk[2] = (short)f2bf(hi[0]); pk[3] = (short)f2bf(hi[1]);
      *(short4v*)(void*)&vrow[lane*4] = pk;
    }
    // prefetch next Gperm values (4 coalesced ushort loads, 128B dense per inst)
    if (t + 1 < T_){
      const ushort_t* gp = gp0 + (long)(t+1)*131072;
      #pragma unroll
      for (int g = 0; g < 4; g++) gb[g] = gp[g*64];
    }
    // epilogue: single row r=0; lane (quad,u) = batch blk*4+quad, j = w*16+u
    {
      float iv = fsig (acc[0][0]);
      float fv = fsig (acc[1][0]);
      float gv = ftanh(acc[2][0]);
      float ov = fsig (acc[3][0]);
      float c  = fv * c_reg + iv * gv;
      c_reg = c;
      float h  = ov * ftanh(c);
      int p8 = __builtin_amdgcn_cvt_pk_fp8_f32(h, h, 0, false);
      h8[(t+1)&1][quad*4][w*16 + u] = (char)(p8 & 0xff);
    }
  }
  __syncthreads();
  // final dump: h(511) lives in h8[0]
  if (w < 4){
    ushort_t* vrow = vbf + ((long)(T_-1) * B_ + blk*4 + w) * 768;
    uint32 p = *(const uint32*)(const void*)&h8[0][4*w][lane*4];
    float2v lo = __builtin_amdgcn_cvt_pk_f32_fp8(p, false);
    float2v hi = __builtin_amdgcn_cvt_pk_f32_fp8(p, true);
    short4v pk;
    pk[0] = (short)f2bf(lo[0]); pk[1] = (short)f2bf(lo[1]);
    pk[2] = (short)f2bf(hi[0]); pk[3] = (short)f2bf(hi[1]);
    *(short4v*)(void*)&vrow[lane*4] = pk;
  }
}

extern "C" void kernel_launch(void* const* d_in, const int* in_sizes, int n_in,
                              void* d_out, int out_size, void* d_ws, size_t ws_size,
                              hipStream_t stream){
  (void)in_sizes; (void)n_in; (void)out_size; (void)ws_size;
  const float* enc     = (const float*)d_in[0];
  const int*   sep     = (const int*)  d_in[1];
  const int*   pos_ids = (const int*)  d_in[2];
  const int*   len     = (const int*)  d_in[3];
  const float* pos_emb = (const float*)d_in[4];
  const float* wl_emb  = (const float*)d_in[5];
  const float* fcW     = (const float*)d_in[6];
  const float* fcb     = (const float*)d_in[7];
  const float* W_ih    = (const float*)d_in[8];
  const float* W_hh    = (const float*)d_in[9];
  const float* b_ih    = (const float*)d_in[10];
  const float* b_hh    = (const float*)d_in[11];
  const float* combW   = (const float*)d_in[12];

  char* ws = (char*)d_ws;
  int*      ls    = (int*)     (ws + OFF_LS);
  int*      lp    = (int*)     (ws + OFF_LP);
  int*      wid   = (int*)     (ws + OFF_WID);
  float*    inv   = (float*)   (ws + OFF_INV);
  float*    posW  = (float*)   (ws + OFF_POSW);
  float*    wlW   = (float*)   (ws + OFF_WLW);
  float*    biasg = (float*)   (ws + OFF_BIASG);
  char*     whh8  = (char*)    (ws + OFF_WHH);
  ushort_t* wih   = (ushort_t*)(ws + OFF_WIH);
  ushort_t* wenc  = (ushort_t*)(ws + OFF_WENC);
  ushort_t* combwb= (ushort_t*)(ws + OFF_COMBW);
  ushort_t* ecw   = (ushort_t*)(ws + OFF_ECW);
  ushort_t* zbf   = (ushort_t*)(ws + OFF_Z);
  ushort_t* gperm = (ushort_t*)(ws + OFF_GPERM);
  ushort_t* vbf   = (ushort_t*)(ws + OFF_VBF);

  k_scan<<<2, 64, 0, stream>>>(sep, pos_ids, ls, lp, wid, inv);
  k_encbf<<<BT_, 256, 0, stream>>>(enc, vbf);
  k_small<<<2530, 256, 0, stream>>>(pos_emb, wl_emb, fcW, W_ih, W_hh, b_ih, b_hh, combW,
                                    posW, wlW, biasg, whh8, wih, wenc, combwb);
  // E = enc @ Wenc^T  (rows time-major); n-fast grid: A panel read once
  k_gemm<0><<<dim3(4, BT_/64), 256, 0, stream>>>(vbf + 256, 768L, wenc, 512, LIN_, ecw, nullptr, nullptr);
  // exclusive cumsum over t (in place) -> CW
  k_cum200<<<B_, 256, 0, stream>>>(ecw);
  // z = tanh(...)
  k_z<<<BT_, 256, 0, stream>>>(ecw, ls, lp, wid, inv, posW, wlW, fcb, zbf);
  // Gperm = z @ W_ih^T + biases, written in k_rec's [t][blk][w][g][u][qd] layout
  k_gemm<1><<<dim3(16, BT_/64), 256, 0, stream>>>(zbf, (long)LINP_, wih, LINP_, G4_, gperm, biasg, nullptr);
  // LSTM recurrence (32 blocks x 16 waves, round-2 468us structure)
  k_rec<<<32, 1024, 0, stream>>>(gperm, whh8, vbf);
  // logits = [hs, enc] @ combine_W^T, masked, scattered to b-major output
  k_gemm<2><<<dim3(1, BT_/64), 256, 0, stream>>>(vbf, 768L, combwb, 768, SP_, d_out, nullptr, len);
}

// Round 4
// 883.280 us; speedup vs baseline: 1.1862x; 1.1584x over previous
//
#include <hip/hip_runtime.h>

typedef unsigned short ushort_t;
typedef unsigned int uint32;
typedef __attribute__((ext_vector_type(8))) short short8;
typedef __attribute__((ext_vector_type(4))) short short4v;
typedef __attribute__((ext_vector_type(4))) float floatx4;
typedef __attribute__((ext_vector_type(2))) float float2v;
typedef __attribute__((ext_vector_type(8))) int intx8;

#define B_    128
#define T_    512
#define H_    256
#define H2_   512
#define LIN_  200
#define LINP_ 224
#define G4_   1024
#define SP_   58
#define BT_   (B_*T_)

// ---------- ws layout (bytes) ----------
#define OFF_LS     0UL          // int  [B,T]      262144
#define OFF_LP     262144UL     // int  [B,T]      262144
#define OFF_WID    524288UL     // int  [B,T]      262144
#define OFF_INV    786432UL     // f32  [B,T]      262144
#define OFF_POSW   1212416UL    // f32  [32][200]   25600
#define OFF_WLW    1238016UL    // f32  [8][200]     6400
#define OFF_BIASG  1244416UL    // f32  [1024]       4096
#define OFF_WHH    1248512UL    // fp8  [1024][256] 262144
#define OFF_WIH    1772800UL    // bf16 [1024][224] 458752
#define OFF_WENC   2231552UL    // bf16 [200][512]  204800
#define OFF_COMBW  2436352UL    // bf16 [58][768]    89088
#define OFF_ECW    2525440UL    // bf16 [65536][200] time-major rows (t*128+b)
#define OFF_Z      28739840UL   // bf16 [65536][224] time-major rows
#define OFF_GPERM  58099968UL   // bf16 swizzled [512][32 blk][16 w][4 g][16 u][4 qd]
#define OFF_VBF    192317696UL  // bf16 [65536][768] time-major rows (0:256 hs, 256:768 enc)

__device__ __forceinline__ ushort_t f2bf(float x){
  uint32 u = __float_as_uint(x);
  u += 0x7fffu + ((u >> 16) & 1u);
  return (ushort_t)(u >> 16);
}
__device__ __forceinline__ float bf2f(ushort_t v){
  return __uint_as_float(((uint32)v) << 16);
}
// fast sigmoid/tanh (exp2-based __expf + v_rcp); |err| ~1e-5, way inside bf16
__device__ __forceinline__ float fsig(float x){
  return __builtin_amdgcn_rcpf(1.0f + __expf(-x));
}
__device__ __forceinline__ float ftanh(float x){
  return 1.0f - 2.0f * __builtin_amdgcn_rcpf(1.0f + __expf(2.0f * x));
}

// ---------- scan: last_sep / wordlen / last_pos, parallel Hillis-Steele ----------
// (old serial version: 128 threads x 512 dep iterations, stride-2KB uncoalesced)
__global__ __launch_bounds__(512) void k_scan(const int* __restrict__ sep, const int* __restrict__ pos_ids,
                       int* __restrict__ ls, int* __restrict__ lp,
                       int* __restrict__ wid, float* __restrict__ inv){
  int b = blockIdx.x, t = threadIdx.x;
  __shared__ int sm[512];
  int v = (sep[b*T_ + t] > 0) ? t : 0;
  sm[t] = v;
  __syncthreads();
  #pragma unroll
  for (int off = 1; off < 512; off <<= 1){
    int o = (t >= off) ? sm[t - off] : 0;
    __syncthreads();
    v = (o > v) ? o : v;
    sm[t] = v;
    __syncthreads();
  }
  int l = (t == 0) ? 0 : sm[t - 1];      // last sep strictly before t
  int wlen = t - l;
  int wsv  = (wlen < 1) ? 1 : wlen;
  ls[b*T_ + t]  = l;
  lp[b*T_ + t]  = pos_ids[b*T_ + l];
  wid[b*T_ + t] = (wsv > 7) ? 7 : wsv;
  inv[b*T_ + t] = 1.0f / (float)wsv;
}

// ---------- enc -> bf16 into vbf[t*128+b][256:768] ----------
__global__ __launch_bounds__(256) void k_encbf(const float* __restrict__ enc, ushort_t* __restrict__ vbf){
  long row = blockIdx.x;           // b*512 + t (matches enc layout)
  int b = (int)(row >> 9), t = (int)(row & (T_-1));
  int c = threadIdx.x;
  const float* e = enc + row * H2_;
  ushort_t* v = vbf + ((long)t * B_ + b) * 768 + 256;
  v[c]       = f2bf(e[c]);
  v[c + 256] = f2bf(e[c + 256]);
}

// ---------- small precomputes / weight conversions ----------
__global__ __launch_bounds__(256) void k_small(
    const float* __restrict__ pos_emb, const float* __restrict__ wl_emb,
    const float* __restrict__ fcW, const float* __restrict__ W_ih,
    const float* __restrict__ W_hh, const float* __restrict__ b_ih,
    const float* __restrict__ b_hh, const float* __restrict__ combW,
    float* __restrict__ posW, float* __restrict__ wlW, float* __restrict__ biasg,
    char* __restrict__ whh8, ushort_t* __restrict__ wih,
    ushort_t* __restrict__ wenc, ushort_t* __restrict__ combwb){
  int idx = blockIdx.x * 256 + threadIdx.x;
  if (idx < 6400){
    int p = idx / 200, l = idx % 200;
    float s = 0.f;
    for (int d = 0; d < 50; d++) s += pos_emb[p*50 + d] * fcW[l*582 + d];
    posW[idx] = s; return;
  }
  idx -= 6400;
  if (idx < 1600){
    int w = idx / 200, l = idx % 200;
    float s = 0.f;
    for (int d = 0; d < 20; d++) s += wl_emb[w*20 + d] * fcW[l*582 + 562 + d];
    wlW[idx] = s; return;
  }
  idx -= 1600;
  if (idx < 1024){ biasg[idx] = b_ih[idx] + b_hh[idx]; return; }
  idx -= 1024;
  if (idx < 262144){
    int p8 = __builtin_amdgcn_cvt_pk_fp8_f32(W_hh[idx], W_hh[idx], 0, false);
    whh8[idx] = (char)(p8 & 0xff);
    return;
  }
  idx -= 262144;
  if (idx < 229376){
    int n = idx / 224, k = idx % 224;
    wih[idx] = (k < 200) ? f2bf(W_ih[n*200 + k]) : (ushort_t)0;
    return;
  }
  idx -= 229376;
  if (idx < 102400){
    int l = idx / 512, c = idx % 512;
    wenc[idx] = f2bf(fcW[l*582 + 50 + c]); return;
  }
  idx -= 102400;
  if (idx < 44544){ combwb[idx] = f2bf(combW[idx]); return; }
}

// ---------- generic 64x64 bf16 MFMA GEMM: C[m,n] = sum_k A[m,k]*B[n,k] ----------
// Grid: x = N-tiles (fast dim), y = M-blocks.
// EPI 0: bf16 out [m][Nvalid]
// EPI 1: +bias, bf16 out in k_rec Gperm layout [t][blk32][w16][g4][u16][qd4]
// EPI 2: masked fp32 logits, m time-major -> out b-major [b*T+t][58]
template<int EPI>
__global__ __launch_bounds__(256) void k_gemm(
    const ushort_t* __restrict__ A, long lda,
    const ushort_t* __restrict__ Bm, int K, int Nvalid,
    void* __restrict__ Cout, const float* __restrict__ bias, const int* __restrict__ len){
  __shared__ __attribute__((aligned(16))) ushort_t As[64][48];
  __shared__ __attribute__((aligned(16))) ushort_t Bs[64][48];
  int tid  = threadIdx.x;
  int lane = tid & 63, wave = tid >> 6;
  int u = lane & 15, quad = lane >> 4;
  int mh = wave >> 1, nh = wave & 1;
  long m0 = (long)blockIdx.y * 64;
  int  n0 = blockIdx.x * 64;
  int lrow = tid >> 2;
  int lcol = (tid & 3) * 8;
  const ushort_t* Arow = A + (m0 + lrow) * lda + lcol;
  bool bvalid = (n0 + lrow) < Nvalid;
  const ushort_t* Brow = Bm + (long)(n0 + lrow) * K + lcol;
  floatx4 acc[2][2] = {};
  for (int k = 0; k < K; k += 32){
    short8 av = *(const short8*)(const void*)(Arow + k);
    short8 bv = {0,0,0,0,0,0,0,0};
    if (bvalid) bv = *(const short8*)(const void*)(Brow + k);
    __syncthreads();
    *(short8*)(void*)&As[lrow][lcol] = av;
    *(short8*)(void*)&Bs[lrow][lcol] = bv;
    __syncthreads();
    short8 a0 = *(const short8*)(const void*)&As[mh*32 + u][quad*8];
    short8 a1 = *(const short8*)(const void*)&As[mh*32 + 16 + u][quad*8];
    short8 b0 = *(const short8*)(const void*)&Bs[nh*32 + u][quad*8];
    short8 b1 = *(const short8*)(const void*)&Bs[nh*32 + 16 + u][quad*8];
    acc[0][0] = __builtin_amdgcn_mfma_f32_16x16x32_bf16(a0, b0, acc[0][0], 0, 0, 0);
    acc[0][1] = __builtin_amdgcn_mfma_f32_16x16x32_bf16(a0, b1, acc[0][1], 0, 0, 0);
    acc[1][0] = __builtin_amdgcn_mfma_f32_16x16x32_bf16(a1, b0, acc[1][0], 0, 0, 0);
    acc[1][1] = __builtin_amdgcn_mfma_f32_16x16x32_bf16(a1, b1, acc[1][1], 0, 0, 0);
  }
  if (EPI == 1){
    #pragma unroll
    for (int mi = 0; mi < 2; mi++){
      #pragma unroll
      for (int ni = 0; ni < 2; ni++){
        long mm = m0 + mh*32 + mi*16 + quad*4;     // 4 r's = 4 consecutive b (qd 0..3)
        int n = n0 + nh*32 + ni*16 + u;
        float bv = bias[n];
        int t = (int)(mm >> 7);
        int b = (int)(mm & 127);
        int blk = b >> 2;                           // b % 4 == 0 here
        int g = n >> 8, j = n & 255, ut = j & 15, jt = j >> 4;
        long idx = ((((long)t*32 + blk)*16 + jt)*4 + g)*64 + ut*4;
        short4v pk;
        #pragma unroll
        for (int r = 0; r < 4; r++) pk[r] = (short)f2bf(acc[mi][ni][r] + bv);
        *(short4v*)(void*)((ushort_t*)Cout + idx) = pk;
      }
    }
  } else {
    for (int mi = 0; mi < 2; mi++){
      for (int ni = 0; ni < 2; ni++){
        for (int r = 0; r < 4; r++){
          long m = m0 + mh*32 + mi*16 + quad*4 + r;
          int  n = n0 + nh*32 + ni*16 + u;
          float v = acc[mi][ni][r];
          if (EPI == 0){
            if (n < Nvalid) ((ushort_t*)Cout)[m * Nvalid + n] = f2bf(v);
          } else {
            if (n < Nvalid){
              int t = (int)(m >> 7); int b = (int)(m & 127);
              float o = (t < len[b]) ? v : 0.0f;
              if (t == 0 && n == 0) o = -1e30f;
              ((float*)Cout)[((long)b * T_ + t) * SP_ + n] = o;
            }
          }
        }
      }
    }
  }
}

// ---------- exclusive cumsum over t, in place on E (bf16, time-major rows) ----------
__global__ __launch_bounds__(256) void k_cum200(ushort_t* __restrict__ E){
  int b = blockIdx.x;
  int c = threadIdx.x;
  if (c >= LIN_) return;
  float acc = 0.f;
  ushort_t* p = E + (long)b * LIN_ + c;      // row (t*128+b)
  const long rs = (long)B_ * LIN_;           // per-t stride
  for (int t0 = 0; t0 < T_; t0 += 16){
    float vv[16];
    #pragma unroll
    for (int i = 0; i < 16; i++) vv[i] = bf2f(p[i*rs]);
    #pragma unroll
    for (int i = 0; i < 16; i++){ p[i*rs] = f2bf(acc); acc += vv[i]; }
    p += 16*rs;
  }
}

// ---------- z = tanh((CW[t]-CW[ls])*inv + posW + wlW + b), t=0 -> 0, pad K to 224 ----------
__global__ __launch_bounds__(256) void k_z(
    const ushort_t* __restrict__ CW, const int* __restrict__ ls, const int* __restrict__ lp,
    const int* __restrict__ wid, const float* __restrict__ inv,
    const float* __restrict__ posW, const float* __restrict__ wlW,
    const float* __restrict__ fcb, ushort_t* __restrict__ zbf){
  int m = blockIdx.x;               // time-major row t*128+b
  int l = threadIdx.x;
  if (l >= LINP_) return;
  int t = m >> 7;
  int b = m & 127;
  int ar = b * T_ + t;              // b-major aux index
  ushort_t o = 0;
  if (t != 0 && l < LIN_){
    int lsv = ls[ar];
    float x = bf2f(CW[(long)m * LIN_ + l]) - bf2f(CW[((long)lsv * B_ + b) * LIN_ + l]);
    x = x * inv[ar] + posW[lp[ar]*LIN_ + l] + wlW[wid[ar]*LIN_ + l] + fcb[l];
    o = f2bf(ftanh(x));
  }
  zbf[(long)m * LINP_ + l] = o;
}

// ---------- LSTM recurrence: 32 blocks x 1024 threads, NB=4 batches/block ----------
// Batches at A-rows {0,4,8,12} -> every lane owns one (batch=quad, j=w*16+u) output.
// THIS ROUND: MFMA/VALU interleave. All 16 waves are barrier-lockstepped, so the
// old all-MFMA-then-all-epilogue order serialized the 1104cyc/SIMD matrix burst
// with the ~450cyc/SIMD VALU burst. Now: vbf dump + Gperm prefetch issue BEFORE
// the MFMA cluster (VMEM/LDS pipes), and gate activations i,f are computed between
// the g0/g1 and g2/g3 MFMA pairs so VALU co-issues under the matrix pipe (m114).
__global__ __launch_bounds__(1024, 4) void k_rec(
    const ushort_t* __restrict__ Gperm, const char* __restrict__ whh8,
    ushort_t* __restrict__ vbf){
  int blk  = blockIdx.x;                      // 0..31: batches blk*4 .. blk*4+3
  int tid  = threadIdx.x;
  int lane = tid & 63, w = tid >> 6;          // w in [0,16): hidden j-tile
  int u = lane & 15, quad = lane >> 4;        // quad = local batch index
  __shared__ __attribute__((aligned(16))) char h8[2][16][272];   // row stride 272
  for (int i = tid; i < (int)(sizeof(h8)/4); i += 1024) ((int*)h8)[i] = 0;

  // W_hh fp8 B-fragments (MX K=128): gate g, cols w*16+u; pinned in VGPRs.
  intx8 wfx[4][2];
  #pragma unroll
  for (int g = 0; g < 4; g++){
    int grow = g*256 + w*16 + u;
    #pragma unroll
    for (int kc = 0; kc < 2; kc++){
      intx8 v = *(const intx8*)(const void*)(whh8 + (long)grow*256 + kc*128 + quad*32);
      asm volatile("" : "+v"(v));
      wfx[g][kc] = v;
    }
  }
  float c_reg = 0.f;
  floatx4 acc[4] = {};   // element 0 rebuilt each step; elements 1..3 stay 0 forever

  // Gperm[t][blk][w][g][u][qd]: lane (quad,u) reads gate g at g*64 + u*4 + quad
  const ushort_t* gp0 = Gperm + ((long)blk*16 + w)*256 + (long)u*4 + quad;
  ushort_t gb[4];
  #pragma unroll
  for (int g = 0; g < 4; g++) gb[g] = gp0[g*64];

  for (int t = 0; t < T_; t++){
    #pragma unroll
    for (int g = 0; g < 4; g++) acc[g][0] = bf2f(gb[g]);
    __syncthreads();                       // h8[t&1] = h(t-1) ready
    intx8 af0 = *(const intx8*)(const void*)&h8[t & 1][u][quad*32];
    intx8 af1 = *(const intx8*)(const void*)&h8[t & 1][u][128 + quad*32];
    // EARLY: coalesced vbf dump of h(t-1) (independent of MFMAs; VMEM pipe)
    if (t && w < 4){
      ushort_t* vrow = vbf + ((long)(t-1) * B_ + blk*4 + w) * 768;
      uint32 p = *(const uint32*)(const void*)&h8[t & 1][4*w][lane*4];
      float2v lo = __builtin_amdgcn_cvt_pk_f32_fp8(p, false);
      float2v hi = __builtin_amdgcn_cvt_pk_f32_fp8(p, true);
      short4v pk;
      pk[0] = (short)f2bf(lo[0]); pk[1] = (short)f2bf(lo[1]);
      pk[2] = (short)f2bf(hi[0]); pk[3] = (short)f2bf(hi[1]);
      *(short4v*)(void*)&vrow[lane*4] = pk;
    }
    // EARLY: prefetch next Gperm values (hides HBM latency under MFMAs)
    if (t + 1 < T_){
      const ushort_t* gp = gp0 + (long)(t+1)*131072;
      #pragma unroll
      for (int g = 0; g < 4; g++) gb[g] = gp[g*64];
    }
    // gates i,f
    acc[0] = __builtin_amdgcn_mfma_scale_f32_16x16x128_f8f6f4(
        af0, wfx[0][0], acc[0], 0, 0, 0, 0x7F7F7F7F, 0, 0x7F7F7F7F);
    acc[0] = __builtin_amdgcn_mfma_scale_f32_16x16x128_f8f6f4(
        af1, wfx[0][1], acc[0], 0, 0, 0, 0x7F7F7F7F, 0, 0x7F7F7F7F);
    acc[1] = __builtin_amdgcn_mfma_scale_f32_16x16x128_f8f6f4(
        af0, wfx[1][0], acc[1], 0, 0, 0, 0x7F7F7F7F, 0, 0x7F7F7F7F);
    acc[1] = __builtin_amdgcn_mfma_scale_f32_16x16x128_f8f6f4(
        af1, wfx[1][1], acc[1], 0, 0, 0, 0x7F7F7F7F, 0, 0x7F7F7F7F);
    // i,f activations co-issue on VALU while g,o MFMAs occupy the matrix pipe
    float iv = fsig (acc[0][0]);
    float fv = fsig (acc[1][0]);
    // gates g,o
    acc[2] = __builtin_amdgcn_mfma_scale_f32_16x16x128_f8f6f4(
        af0, wfx[2][0], acc[2], 0, 0, 0, 0x7F7F7F7F, 0, 0x7F7F7F7F);
    acc[2] = __builtin_amdgcn_mfma_scale_f32_16x16x128_f8f6f4(
        af1, wfx[2][1], acc[2], 0, 0, 0, 0x7F7F7F7F, 0, 0x7F7F7F7F);
    acc[3] = __builtin_amdgcn_mfma_scale_f32_16x16x128_f8f6f4(
        af0, wfx[3][0], acc[3], 0, 0, 0, 0x7F7F7F7F, 0, 0x7F7F7F7F);
    acc[3] = __builtin_amdgcn_mfma_scale_f32_16x16x128_f8f6f4(
        af1, wfx[3][1], acc[3], 0, 0, 0, 0x7F7F7F7F, 0, 0x7F7F7F7F);
    float gv = ftanh(acc[2][0]);
    float ov = fsig (acc[3][0]);
    float c  = fv * c_reg + iv * gv;
    c_reg = c;
    float h  = ov * ftanh(c);
    int p8 = __builtin_amdgcn_cvt_pk_fp8_f32(h, h, 0, false);
    h8[(t+1)&1][quad*4][w*16 + u] = (char)(p8 & 0xff);
  }
  __syncthreads();
  // final dump: h(511) lives in h8[0]
  if (w < 4){
    ushort_t* vrow = vbf + ((long)(T_-1) * B_ + blk*4 + w) * 768;
    uint32 p = *(const uint32*)(const void*)&h8[0][4*w][lane*4];
    float2v lo = __builtin_amdgcn_cvt_pk_f32_fp8(p, false);
    float2v hi = __builtin_amdgcn_cvt_pk_f32_fp8(p, true);
    short4v pk;
    pk[0] = (short)f2bf(lo[0]); pk[1] = (short)f2bf(lo[1]);
    pk[2] = (short)f2bf(hi[0]); pk[3] = (short)f2bf(hi[1]);
    *(short4v*)(void*)&vrow[lane*4] = pk;
  }
}

extern "C" void kernel_launch(void* const* d_in, const int* in_sizes, int n_in,
                              void* d_out, int out_size, void* d_ws, size_t ws_size,
                              hipStream_t stream){
  (void)in_sizes; (void)n_in; (void)out_size; (void)ws_size;
  const float* enc     = (const float*)d_in[0];
  const int*   sep     = (const int*)  d_in[1];
  const int*   pos_ids = (const int*)  d_in[2];
  const int*   len     = (const int*)  d_in[3];
  const float* pos_emb = (const float*)d_in[4];
  const float* wl_emb  = (const float*)d_in[5];
  const float* fcW     = (const float*)d_in[6];
  const float* fcb     = (const float*)d_in[7];
  const float* W_ih    = (const float*)d_in[8];
  const float* W_hh    = (const float*)d_in[9];
  const float* b_ih    = (const float*)d_in[10];
  const float* b_hh    = (const float*)d_in[11];
  const float* combW   = (const float*)d_in[12];

  char* ws = (char*)d_ws;
  int*      ls    = (int*)     (ws + OFF_LS);
  int*      lp    = (int*)     (ws + OFF_LP);
  int*      wid   = (int*)     (ws + OFF_WID);
  float*    inv   = (float*)   (ws + OFF_INV);
  float*    posW  = (float*)   (ws + OFF_POSW);
  float*    wlW   = (float*)   (ws + OFF_WLW);
  float*    biasg = (float*)   (ws + OFF_BIASG);
  char*     whh8  = (char*)    (ws + OFF_WHH);
  ushort_t* wih   = (ushort_t*)(ws + OFF_WIH);
  ushort_t* wenc  = (ushort_t*)(ws + OFF_WENC);
  ushort_t* combwb= (ushort_t*)(ws + OFF_COMBW);
  ushort_t* ecw   = (ushort_t*)(ws + OFF_ECW);
  ushort_t* zbf   = (ushort_t*)(ws + OFF_Z);
  ushort_t* gperm = (ushort_t*)(ws + OFF_GPERM);
  ushort_t* vbf   = (ushort_t*)(ws + OFF_VBF);

  k_scan<<<B_, 512, 0, stream>>>(sep, pos_ids, ls, lp, wid, inv);
  k_encbf<<<BT_, 256, 0, stream>>>(enc, vbf);
  k_small<<<2530, 256, 0, stream>>>(pos_emb, wl_emb, fcW, W_ih, W_hh, b_ih, b_hh, combW,
                                    posW, wlW, biasg, whh8, wih, wenc, combwb);
  // E = enc @ Wenc^T  (rows time-major)
  k_gemm<0><<<dim3(4, BT_/64), 256, 0, stream>>>(vbf + 256, 768L, wenc, 512, LIN_, ecw, nullptr, nullptr);
  // exclusive cumsum over t (in place) -> CW
  k_cum200<<<B_, 256, 0, stream>>>(ecw);
  // z = tanh(...)
  k_z<<<BT_, 256, 0, stream>>>(ecw, ls, lp, wid, inv, posW, wlW, fcb, zbf);
  // Gperm = z @ W_ih^T + biases, written in k_rec's [t][blk][w][g][u][qd] layout
  k_gemm<1><<<dim3(16, BT_/64), 256, 0, stream>>>(zbf, (long)LINP_, wih, LINP_, G4_, gperm, biasg, nullptr);
  // LSTM recurrence (32 blocks x 16 waves, MFMA/VALU interleaved step)
  k_rec<<<32, 1024, 0, stream>>>(gperm, whh8, vbf);
  // logits = [hs, enc] @ combine_W^T, masked, scattered to b-major output
  k_gemm<2><<<dim3(1, BT_/64), 256, 0, stream>>>(vbf, 768L, combwb, 768, SP_, d_out, nullptr, len);
}

// Round 5
// 879.157 us; speedup vs baseline: 1.1918x; 1.0047x over previous
//
#include <hip/hip_runtime.h>

typedef unsigned short ushort_t;
typedef unsigned int uint32;
typedef __attribute__((ext_vector_type(8))) short short8;
typedef __attribute__((ext_vector_type(4))) short short4v;
typedef __attribute__((ext_vector_type(4))) float floatx4;
typedef __attribute__((ext_vector_type(2))) float float2v;
typedef __attribute__((ext_vector_type(8))) int intx8;

#define B_    128
#define T_    512
#define H_    256
#define H2_   512
#define LIN_  200
#define LINP_ 224
#define G4_   1024
#define SP_   58
#define BT_   (B_*T_)

// ---------- ws layout (bytes) ----------
#define OFF_LS     0UL          // int  [B,T]      262144
#define OFF_LP     262144UL     // int  [B,T]      262144
#define OFF_WID    524288UL     // int  [B,T]      262144
#define OFF_INV    786432UL     // f32  [B,T]      262144
#define OFF_POSW   1212416UL    // f32  [32][200]   25600
#define OFF_WLW    1238016UL    // f32  [8][200]     6400
#define OFF_BIASG  1244416UL    // f32  [1024]       4096
#define OFF_WHH    1248512UL    // fp8  [1024][256] 262144
#define OFF_WIH    1772800UL    // bf16 [1024][224] 458752
#define OFF_WENC   2231552UL    // bf16 [200][512]  204800
#define OFF_COMBW  2436352UL    // bf16 [58][768]    89088
#define OFF_ECW    2525440UL    // bf16 [65536][200] time-major rows (t*128+b)
#define OFF_Z      28739840UL   // bf16 [65536][224] time-major rows
#define OFF_GPERM  58099968UL   // bf16 swizzled [512][32 blk][16 w][4 g][16 u][4 qd]
#define OFF_VBF    192317696UL  // bf16 [65536][768] time-major rows (0:256 hs, 256:768 enc)

__device__ __forceinline__ ushort_t f2bf(float x){
  uint32 u = __float_as_uint(x);
  u += 0x7fffu + ((u >> 16) & 1u);
  return (ushort_t)(u >> 16);
}
__device__ __forceinline__ float bf2f(ushort_t v){
  return __uint_as_float(((uint32)v) << 16);
}
// fast sigmoid/tanh (exp2-based __expf + v_rcp); |err| ~1e-5, way inside bf16
__device__ __forceinline__ float fsig(float x){
  return __builtin_amdgcn_rcpf(1.0f + __expf(-x));
}
__device__ __forceinline__ float ftanh(float x){
  return 1.0f - 2.0f * __builtin_amdgcn_rcpf(1.0f + __expf(2.0f * x));
}

// ---------- scan: last_sep / wordlen / last_pos, parallel Hillis-Steele ----------
__global__ __launch_bounds__(512) void k_scan(const int* __restrict__ sep, const int* __restrict__ pos_ids,
                       int* __restrict__ ls, int* __restrict__ lp,
                       int* __restrict__ wid, float* __restrict__ inv){
  int b = blockIdx.x, t = threadIdx.x;
  __shared__ int sm[512];
  int v = (sep[b*T_ + t] > 0) ? t : 0;
  sm[t] = v;
  __syncthreads();
  #pragma unroll
  for (int off = 1; off < 512; off <<= 1){
    int o = (t >= off) ? sm[t - off] : 0;
    __syncthreads();
    v = (o > v) ? o : v;
    sm[t] = v;
    __syncthreads();
  }
  int l = (t == 0) ? 0 : sm[t - 1];      // last sep strictly before t
  int wlen = t - l;
  int wsv  = (wlen < 1) ? 1 : wlen;
  ls[b*T_ + t]  = l;
  lp[b*T_ + t]  = pos_ids[b*T_ + l];
  wid[b*T_ + t] = (wsv > 7) ? 7 : wsv;
  inv[b*T_ + t] = 1.0f / (float)wsv;
}

// ---------- enc -> bf16 into vbf[t*128+b][256:768] ----------
__global__ __launch_bounds__(256) void k_encbf(const float* __restrict__ enc, ushort_t* __restrict__ vbf){
  long row = blockIdx.x;           // b*512 + t (matches enc layout)
  int b = (int)(row >> 9), t = (int)(row & (T_-1));
  int c = threadIdx.x;
  const float* e = enc + row * H2_;
  ushort_t* v = vbf + ((long)t * B_ + b) * 768 + 256;
  v[c]       = f2bf(e[c]);
  v[c + 256] = f2bf(e[c + 256]);
}

// ---------- small precomputes / weight conversions ----------
__global__ __launch_bounds__(256) void k_small(
    const float* __restrict__ pos_emb, const float* __restrict__ wl_emb,
    const float* __restrict__ fcW, const float* __restrict__ W_ih,
    const float* __restrict__ W_hh, const float* __restrict__ b_ih,
    const float* __restrict__ b_hh, const float* __restrict__ combW,
    float* __restrict__ posW, float* __restrict__ wlW, float* __restrict__ biasg,
    char* __restrict__ whh8, ushort_t* __restrict__ wih,
    ushort_t* __restrict__ wenc, ushort_t* __restrict__ combwb){
  int idx = blockIdx.x * 256 + threadIdx.x;
  if (idx < 6400){
    int p = idx / 200, l = idx % 200;
    float s = 0.f;
    for (int d = 0; d < 50; d++) s += pos_emb[p*50 + d] * fcW[l*582 + d];
    posW[idx] = s; return;
  }
  idx -= 6400;
  if (idx < 1600){
    int w = idx / 200, l = idx % 200;
    float s = 0.f;
    for (int d = 0; d < 20; d++) s += wl_emb[w*20 + d] * fcW[l*582 + 562 + d];
    wlW[idx] = s; return;
  }
  idx -= 1600;
  if (idx < 1024){ biasg[idx] = b_ih[idx] + b_hh[idx]; return; }
  idx -= 1024;
  if (idx < 262144){
    int p8 = __builtin_amdgcn_cvt_pk_fp8_f32(W_hh[idx], W_hh[idx], 0, false);
    whh8[idx] = (char)(p8 & 0xff);
    return;
  }
  idx -= 262144;
  if (idx < 229376){
    int n = idx / 224, k = idx % 224;
    wih[idx] = (k < 200) ? f2bf(W_ih[n*200 + k]) : (ushort_t)0;
    return;
  }
  idx -= 229376;
  if (idx < 102400){
    int l = idx / 512, c = idx % 512;
    wenc[idx] = f2bf(fcW[l*582 + 50 + c]); return;
  }
  idx -= 102400;
  if (idx < 44544){ combwb[idx] = f2bf(combW[idx]); return; }
}

// ---------- generic 64x64 bf16 MFMA GEMM: C[m,n] = sum_k A[m,k]*B[n,k] ----------
// Grid: x = N-tiles (fast dim), y = M-blocks.
// EPI 0: bf16 out [m][Nvalid]
// EPI 1: +bias, bf16 out in k_rec Gperm layout [t][blk32][w16][g4][u16][qd4]
// EPI 2: masked fp32 logits, m time-major -> out b-major [b*T+t][58]
template<int EPI>
__global__ __launch_bounds__(256) void k_gemm(
    const ushort_t* __restrict__ A, long lda,
    const ushort_t* __restrict__ Bm, int K, int Nvalid,
    void* __restrict__ Cout, const float* __restrict__ bias, const int* __restrict__ len){
  __shared__ __attribute__((aligned(16))) ushort_t As[64][48];
  __shared__ __attribute__((aligned(16))) ushort_t Bs[64][48];
  int tid  = threadIdx.x;
  int lane = tid & 63, wave = tid >> 6;
  int u = lane & 15, quad = lane >> 4;
  int mh = wave >> 1, nh = wave & 1;
  long m0 = (long)blockIdx.y * 64;
  int  n0 = blockIdx.x * 64;
  int lrow = tid >> 2;
  int lcol = (tid & 3) * 8;
  const ushort_t* Arow = A + (m0 + lrow) * lda + lcol;
  bool bvalid = (n0 + lrow) < Nvalid;
  const ushort_t* Brow = Bm + (long)(n0 + lrow) * K + lcol;
  floatx4 acc[2][2] = {};
  for (int k = 0; k < K; k += 32){
    short8 av = *(const short8*)(const void*)(Arow + k);
    short8 bv = {0,0,0,0,0,0,0,0};
    if (bvalid) bv = *(const short8*)(const void*)(Brow + k);
    __syncthreads();
    *(short8*)(void*)&As[lrow][lcol] = av;
    *(short8*)(void*)&Bs[lrow][lcol] = bv;
    __syncthreads();
    short8 a0 = *(const short8*)(const void*)&As[mh*32 + u][quad*8];
    short8 a1 = *(const short8*)(const void*)&As[mh*32 + 16 + u][quad*8];
    short8 b0 = *(const short8*)(const void*)&Bs[nh*32 + u][quad*8];
    short8 b1 = *(const short8*)(const void*)&Bs[nh*32 + 16 + u][quad*8];
    acc[0][0] = __builtin_amdgcn_mfma_f32_16x16x32_bf16(a0, b0, acc[0][0], 0, 0, 0);
    acc[0][1] = __builtin_amdgcn_mfma_f32_16x16x32_bf16(a0, b1, acc[0][1], 0, 0, 0);
    acc[1][0] = __builtin_amdgcn_mfma_f32_16x16x32_bf16(a1, b0, acc[1][0], 0, 0, 0);
    acc[1][1] = __builtin_amdgcn_mfma_f32_16x16x32_bf16(a1, b1, acc[1][1], 0, 0, 0);
  }
  if (EPI == 1){
    #pragma unroll
    for (int mi = 0; mi < 2; mi++){
      #pragma unroll
      for (int ni = 0; ni < 2; ni++){
        long mm = m0 + mh*32 + mi*16 + quad*4;     // 4 r's = 4 consecutive b (qd 0..3)
        int n = n0 + nh*32 + ni*16 + u;
        float bv = bias[n];
        int t = (int)(mm >> 7);
        int b = (int)(mm & 127);
        int blk = b >> 2;                           // b % 4 == 0 here
        int g = n >> 8, j = n & 255, ut = j & 15, jt = j >> 4;
        long idx = ((((long)t*32 + blk)*16 + jt)*4 + g)*64 + ut*4;
        short4v pk;
        #pragma unroll
        for (int r = 0; r < 4; r++) pk[r] = (short)f2bf(acc[mi][ni][r] + bv);
        *(short4v*)(void*)((ushort_t*)Cout + idx) = pk;
      }
    }
  } else {
    for (int mi = 0; mi < 2; mi++){
      for (int ni = 0; ni < 2; ni++){
        for (int r = 0; r < 4; r++){
          long m = m0 + mh*32 + mi*16 + quad*4 + r;
          int  n = n0 + nh*32 + ni*16 + u;
          float v = acc[mi][ni][r];
          if (EPI == 0){
            if (n < Nvalid) ((ushort_t*)Cout)[m * Nvalid + n] = f2bf(v);
          } else {
            if (n < Nvalid){
              int t = (int)(m >> 7); int b = (int)(m & 127);
              float o = (t < len[b]) ? v : 0.0f;
              if (t == 0 && n == 0) o = -1e30f;
              ((float*)Cout)[((long)b * T_ + t) * SP_ + n] = o;
            }
          }
        }
      }
    }
  }
}

// ---------- exclusive cumsum over t, in place on E (bf16, time-major rows) ----------
__global__ __launch_bounds__(256) void k_cum200(ushort_t* __restrict__ E){
  int b = blockIdx.x;
  int c = threadIdx.x;
  if (c >= LIN_) return;
  float acc = 0.f;
  ushort_t* p = E + (long)b * LIN_ + c;      // row (t*128+b)
  const long rs = (long)B_ * LIN_;           // per-t stride
  for (int t0 = 0; t0 < T_; t0 += 16){
    float vv[16];
    #pragma unroll
    for (int i = 0; i < 16; i++) vv[i] = bf2f(p[i*rs]);
    #pragma unroll
    for (int i = 0; i < 16; i++){ p[i*rs] = f2bf(acc); acc += vv[i]; }
    p += 16*rs;
  }
}

// ---------- z = tanh((CW[t]-CW[ls])*inv + posW + wlW + b), t=0 -> 0, pad K to 224 ----------
__global__ __launch_bounds__(256) void k_z(
    const ushort_t* __restrict__ CW, const int* __restrict__ ls, const int* __restrict__ lp,
    const int* __restrict__ wid, const float* __restrict__ inv,
    const float* __restrict__ posW, const float* __restrict__ wlW,
    const float* __restrict__ fcb, ushort_t* __restrict__ zbf){
  int m = blockIdx.x;               // time-major row t*128+b
  int l = threadIdx.x;
  if (l >= LINP_) return;
  int t = m >> 7;
  int b = m & 127;
  int ar = b * T_ + t;              // b-major aux index
  ushort_t o = 0;
  if (t != 0 && l < LIN_){
    int lsv = ls[ar];
    float x = bf2f(CW[(long)m * LIN_ + l]) - bf2f(CW[((long)lsv * B_ + b) * LIN_ + l]);
    x = x * inv[ar] + posW[lp[ar]*LIN_ + l] + wlW[wid[ar]*LIN_ + l] + fcb[l];
    o = f2bf(ftanh(x));
  }
  zbf[(long)m * LINP_ + l] = o;
}

// ---------- LSTM recurrence: 32 blocks x 1024 threads, NB=4 batches/block ----------
// Batches at A-rows {0,4,8,12} -> every lane owns one (batch=quad, j=w*16+u) output.
// THIS ROUND (T4): the in-loop barrier is lgkmcnt-only. __syncthreads compiles to
// s_waitcnt vmcnt(0) lgkmcnt(0) + s_barrier, which drained the vbf global store and
// the 4 Gperm prefetch HBM loads to COMPLETION every step (~300-500cyc stall). The
// only cross-wave dependency through the barrier is the h8 ds_write -> ds_read edge,
// which needs lgkmcnt(0) only. gb[] use still gets its compiler-inserted vmcnt wait
// (register dependence), so the prefetch stays correct while staying in flight.
__global__ __launch_bounds__(1024, 4) void k_rec(
    const ushort_t* __restrict__ Gperm, const char* __restrict__ whh8,
    ushort_t* __restrict__ vbf){
  int blk  = blockIdx.x;                      // 0..31: batches blk*4 .. blk*4+3
  int tid  = threadIdx.x;
  int lane = tid & 63, w = tid >> 6;          // w in [0,16): hidden j-tile
  int u = lane & 15, quad = lane >> 4;        // quad = local batch index
  __shared__ __attribute__((aligned(16))) char h8[2][16][272];   // row stride 272
  for (int i = tid; i < (int)(sizeof(h8)/4); i += 1024) ((int*)h8)[i] = 0;

  // W_hh fp8 B-fragments (MX K=128): gate g, cols w*16+u; pinned in VGPRs.
  intx8 wfx[4][2];
  #pragma unroll
  for (int g = 0; g < 4; g++){
    int grow = g*256 + w*16 + u;
    #pragma unroll
    for (int kc = 0; kc < 2; kc++){
      intx8 v = *(const intx8*)(const void*)(whh8 + (long)grow*256 + kc*128 + quad*32);
      asm volatile("" : "+v"(v));
      wfx[g][kc] = v;
    }
  }
  float c_reg = 0.f;
  floatx4 acc[4] = {};   // element 0 rebuilt each step; elements 1..3 stay 0 forever

  // Gperm[t][blk][w][g][u][qd]: lane (quad,u) reads gate g at g*64 + u*4 + quad
  const ushort_t* gp0 = Gperm + ((long)blk*16 + w)*256 + (long)u*4 + quad;
  ushort_t gb[4];
  #pragma unroll
  for (int g = 0; g < 4; g++) gb[g] = gp0[g*64];

  for (int t = 0; t < T_; t++){
    #pragma unroll
    for (int g = 0; g < 4; g++) acc[g][0] = bf2f(gb[g]);
    // lgkm-only barrier: h8 write(t-1) -> read(t) edge; vbf store + Gperm loads
    // stay in flight across the barrier (T4: never drain vmcnt in the loop).
    asm volatile("s_waitcnt lgkmcnt(0)\n\ts_barrier" ::: "memory");
    intx8 af0 = *(const intx8*)(const void*)&h8[t & 1][u][quad*32];
    intx8 af1 = *(const intx8*)(const void*)&h8[t & 1][u][128 + quad*32];
    // EARLY: coalesced vbf dump of h(t-1) (independent of MFMAs; VMEM pipe)
    if (t && w < 4){
      ushort_t* vrow = vbf + ((long)(t-1) * B_ + blk*4 + w) * 768;
      uint32 p = *(const uint32*)(const void*)&h8[t & 1][4*w][lane*4];
      float2v lo = __builtin_amdgcn_cvt_pk_f32_fp8(p, false);
      float2v hi = __builtin_amdgcn_cvt_pk_f32_fp8(p, true);
      short4v pk;
      pk[0] = (short)f2bf(lo[0]); pk[1] = (short)f2bf(lo[1]);
      pk[2] = (short)f2bf(hi[0]); pk[3] = (short)f2bf(hi[1]);
      *(short4v*)(void*)&vrow[lane*4] = pk;
    }
    // EARLY: prefetch next Gperm values (hides HBM latency under MFMAs)
    if (t + 1 < T_){
      const ushort_t* gp = gp0 + (long)(t+1)*131072;
      #pragma unroll
      for (int g = 0; g < 4; g++) gb[g] = gp[g*64];
    }
    // gates i,f
    acc[0] = __builtin_amdgcn_mfma_scale_f32_16x16x128_f8f6f4(
        af0, wfx[0][0], acc[0], 0, 0, 0, 0x7F7F7F7F, 0, 0x7F7F7F7F);
    acc[0] = __builtin_amdgcn_mfma_scale_f32_16x16x128_f8f6f4(
        af1, wfx[0][1], acc[0], 0, 0, 0, 0x7F7F7F7F, 0, 0x7F7F7F7F);
    acc[1] = __builtin_amdgcn_mfma_scale_f32_16x16x128_f8f6f4(
        af0, wfx[1][0], acc[1], 0, 0, 0, 0x7F7F7F7F, 0, 0x7F7F7F7F);
    acc[1] = __builtin_amdgcn_mfma_scale_f32_16x16x128_f8f6f4(
        af1, wfx[1][1], acc[1], 0, 0, 0, 0x7F7F7F7F, 0, 0x7F7F7F7F);
    // i,f activations co-issue on VALU while g,o MFMAs occupy the matrix pipe
    float iv = fsig (acc[0][0]);
    float fv = fsig (acc[1][0]);
    // gates g,o
    acc[2] = __builtin_amdgcn_mfma_scale_f32_16x16x128_f8f6f4(
        af0, wfx[2][0], acc[2], 0, 0, 0, 0x7F7F7F7F, 0, 0x7F7F7F7F);
    acc[2] = __builtin_amdgcn_mfma_scale_f32_16x16x128_f8f6f4(
        af1, wfx[2][1], acc[2], 0, 0, 0, 0x7F7F7F7F, 0, 0x7F7F7F7F);
    acc[3] = __builtin_amdgcn_mfma_scale_f32_16x16x128_f8f6f4(
        af0, wfx[3][0], acc[3], 0, 0, 0, 0x7F7F7F7F, 0, 0x7F7F7F7F);
    acc[3] = __builtin_amdgcn_mfma_scale_f32_16x16x128_f8f6f4(
        af1, wfx[3][1], acc[3], 0, 0, 0, 0x7F7F7F7F, 0, 0x7F7F7F7F);
    float gv = ftanh(acc[2][0]);
    float ov = fsig (acc[3][0]);
    float c  = fv * c_reg + iv * gv;
    c_reg = c;
    float h  = ov * ftanh(c);
    int p8 = __builtin_amdgcn_cvt_pk_fp8_f32(h, h, 0, false);
    h8[(t+1)&1][quad*4][w*16 + u] = (char)(p8 & 0xff);
  }
  __syncthreads();
  // final dump: h(511) lives in h8[0]
  if (w < 4){
    ushort_t* vrow = vbf + ((long)(T_-1) * B_ + blk*4 + w) * 768;
    uint32 p = *(const uint32*)(const void*)&h8[0][4*w][lane*4];
    float2v lo = __builtin_amdgcn_cvt_pk_f32_fp8(p, false);
    float2v hi = __builtin_amdgcn_cvt_pk_f32_fp8(p, true);
    short4v pk;
    pk[0] = (short)f2bf(lo[0]); pk[1] = (short)f2bf(lo[1]);
    pk[2] = (short)f2bf(hi[0]); pk[3] = (short)f2bf(hi[1]);
    *(short4v*)(void*)&vrow[lane*4] = pk;
  }
}

extern "C" void kernel_launch(void* const* d_in, const int* in_sizes, int n_in,
                              void* d_out, int out_size, void* d_ws, size_t ws_size,
                              hipStream_t stream){
  (void)in_sizes; (void)n_in; (void)out_size; (void)ws_size;
  const float* enc     = (const float*)d_in[0];
  const int*   sep     = (const int*)  d_in[1];
  const int*   pos_ids = (const int*)  d_in[2];
  const int*   len     = (const int*)  d_in[3];
  const float* pos_emb = (const float*)d_in[4];
  const float* wl_emb  = (const float*)d_in[5];
  const float* fcW     = (const float*)d_in[6];
  const float* fcb     = (const float*)d_in[7];
  const float* W_ih    = (const float*)d_in[8];
  const float* W_hh    = (const float*)d_in[9];
  const float* b_ih    = (const float*)d_in[10];
  const float* b_hh    = (const float*)d_in[11];
  const float* combW   = (const float*)d_in[12];

  char* ws = (char*)d_ws;
  int*      ls    = (int*)     (ws + OFF_LS);
  int*      lp    = (int*)     (ws + OFF_LP);
  int*      wid   = (int*)     (ws + OFF_WID);
  float*    inv   = (float*)   (ws + OFF_INV);
  float*    posW  = (float*)   (ws + OFF_POSW);
  float*    wlW   = (float*)   (ws + OFF_WLW);
  float*    biasg = (float*)   (ws + OFF_BIASG);
  char*     whh8  = (char*)    (ws + OFF_WHH);
  ushort_t* wih   = (ushort_t*)(ws + OFF_WIH);
  ushort_t* wenc  = (ushort_t*)(ws + OFF_WENC);
  ushort_t* combwb= (ushort_t*)(ws + OFF_COMBW);
  ushort_t* ecw   = (ushort_t*)(ws + OFF_ECW);
  ushort_t* zbf   = (ushort_t*)(ws + OFF_Z);
  ushort_t* gperm = (ushort_t*)(ws + OFF_GPERM);
  ushort_t* vbf   = (ushort_t*)(ws + OFF_VBF);

  k_scan<<<B_, 512, 0, stream>>>(sep, pos_ids, ls, lp, wid, inv);
  k_encbf<<<BT_, 256, 0, stream>>>(enc, vbf);
  k_small<<<2530, 256, 0, stream>>>(pos_emb, wl_emb, fcW, W_ih, W_hh, b_ih, b_hh, combW,
                                    posW, wlW, biasg, whh8, wih, wenc, combwb);
  // E = enc @ Wenc^T  (rows time-major)
  k_gemm<0><<<dim3(4, BT_/64), 256, 0, stream>>>(vbf + 256, 768L, wenc, 512, LIN_, ecw, nullptr, nullptr);
  // exclusive cumsum over t (in place) -> CW
  k_cum200<<<B_, 256, 0, stream>>>(ecw);
  // z = tanh(...)
  k_z<<<BT_, 256, 0, stream>>>(ecw, ls, lp, wid, inv, posW, wlW, fcb, zbf);
  // Gperm = z @ W_ih^T + biases, written in k_rec's [t][blk][w][g][u][qd] layout
  k_gemm<1><<<dim3(16, BT_/64), 256, 0, stream>>>(zbf, (long)LINP_, wih, LINP_, G4_, gperm, biasg, nullptr);
  // LSTM recurrence (32 blocks x 16 waves, lgkm-only in-loop barrier)
  k_rec<<<32, 1024, 0, stream>>>(gperm, whh8, vbf);
  // logits = [hs, enc] @ combine_W^T, masked, scattered to b-major output
  k_gemm<2><<<dim3(1, BT_/64), 256, 0, stream>>>(vbf, 768L, combwb, 768, SP_, d_out, nullptr, len);
}

// Round 6
// 878.082 us; speedup vs baseline: 1.1933x; 1.0012x over previous
//
#include <hip/hip_runtime.h>

typedef unsigned short ushort_t;
typedef unsigned int uint32;
typedef __attribute__((ext_vector_type(8))) short short8;
typedef __attribute__((ext_vector_type(4))) short short4v;
typedef __attribute__((ext_vector_type(4))) float floatx4;
typedef __attribute__((ext_vector_type(2))) float float2v;
typedef __attribute__((ext_vector_type(8))) int intx8;

#define B_    128
#define T_    512
#define H_    256
#define H2_   512
#define LIN_  200
#define LINP_ 224
#define G4_   1024
#define SP_   58
#define BT_   (B_*T_)

// ---------- ws layout (bytes) ----------
#define OFF_LS     0UL          // int  [B,T]      262144
#define OFF_LP     262144UL     // int  [B,T]      262144
#define OFF_WID    524288UL     // int  [B,T]      262144
#define OFF_INV    786432UL     // f32  [B,T]      262144
#define OFF_POSW   1212416UL    // f32  [32][200]   25600
#define OFF_WLW    1238016UL    // f32  [8][200]     6400
#define OFF_BIASG  1244416UL    // f32  [1024]       4096
#define OFF_WHH    1248512UL    // fp8  [1024][256] 262144
#define OFF_WIH    1772800UL    // bf16 [1024][224] 458752
#define OFF_WENC   2231552UL    // bf16 [200][512]  204800
#define OFF_COMBW  2436352UL    // bf16 [58][768]    89088
#define OFF_ECW    2525440UL    // bf16 [65536][200] time-major rows (t*128+b)
#define OFF_Z      28739840UL   // bf16 [65536][224] time-major rows
#define OFF_GPERM  58099968UL   // bf16 swizzled [512][32 blk][16 w][4 g][16 u][4 qd]
#define OFF_VBF    192317696UL  // bf16 [65536][768] time-major rows (0:256 hs, 256:768 enc)

__device__ __forceinline__ ushort_t f2bf(float x){
  uint32 u = __float_as_uint(x);
  u += 0x7fffu + ((u >> 16) & 1u);
  return (ushort_t)(u >> 16);
}
__device__ __forceinline__ float bf2f(ushort_t v){
  return __uint_as_float(((uint32)v) << 16);
}
// fast sigmoid/tanh (exp2-based __expf + v_rcp); |err| ~1e-5, way inside bf16
__device__ __forceinline__ float fsig(float x){
  return __builtin_amdgcn_rcpf(1.0f + __expf(-x));
}
__device__ __forceinline__ float ftanh(float x){
  return 1.0f - 2.0f * __builtin_amdgcn_rcpf(1.0f + __expf(2.0f * x));
}

// ---------- scan: last_sep / wordlen / last_pos, parallel Hillis-Steele ----------
__global__ __launch_bounds__(512) void k_scan(const int* __restrict__ sep, const int* __restrict__ pos_ids,
                       int* __restrict__ ls, int* __restrict__ lp,
                       int* __restrict__ wid, float* __restrict__ inv){
  int b = blockIdx.x, t = threadIdx.x;
  __shared__ int sm[512];
  int v = (sep[b*T_ + t] > 0) ? t : 0;
  sm[t] = v;
  __syncthreads();
  #pragma unroll
  for (int off = 1; off < 512; off <<= 1){
    int o = (t >= off) ? sm[t - off] : 0;
    __syncthreads();
    v = (o > v) ? o : v;
    sm[t] = v;
    __syncthreads();
  }
  int l = (t == 0) ? 0 : sm[t - 1];      // last sep strictly before t
  int wlen = t - l;
  int wsv  = (wlen < 1) ? 1 : wlen;
  ls[b*T_ + t]  = l;
  lp[b*T_ + t]  = pos_ids[b*T_ + l];
  wid[b*T_ + t] = (wsv > 7) ? 7 : wsv;
  inv[b*T_ + t] = 1.0f / (float)wsv;
}

// ---------- enc -> bf16 into vbf[t*128+b][256:768] ----------
__global__ __launch_bounds__(256) void k_encbf(const float* __restrict__ enc, ushort_t* __restrict__ vbf){
  long row = blockIdx.x;           // b*512 + t (matches enc layout)
  int b = (int)(row >> 9), t = (int)(row & (T_-1));
  int c = threadIdx.x;
  const float* e = enc + row * H2_;
  ushort_t* v = vbf + ((long)t * B_ + b) * 768 + 256;
  v[c]       = f2bf(e[c]);
  v[c + 256] = f2bf(e[c + 256]);
}

// ---------- small precomputes / weight conversions ----------
__global__ __launch_bounds__(256) void k_small(
    const float* __restrict__ pos_emb, const float* __restrict__ wl_emb,
    const float* __restrict__ fcW, const float* __restrict__ W_ih,
    const float* __restrict__ W_hh, const float* __restrict__ b_ih,
    const float* __restrict__ b_hh, const float* __restrict__ combW,
    float* __restrict__ posW, float* __restrict__ wlW, float* __restrict__ biasg,
    char* __restrict__ whh8, ushort_t* __restrict__ wih,
    ushort_t* __restrict__ wenc, ushort_t* __restrict__ combwb){
  int idx = blockIdx.x * 256 + threadIdx.x;
  if (idx < 6400){
    int p = idx / 200, l = idx % 200;
    float s = 0.f;
    for (int d = 0; d < 50; d++) s += pos_emb[p*50 + d] * fcW[l*582 + d];
    posW[idx] = s; return;
  }
  idx -= 6400;
  if (idx < 1600){
    int w = idx / 200, l = idx % 200;
    float s = 0.f;
    for (int d = 0; d < 20; d++) s += wl_emb[w*20 + d] * fcW[l*582 + 562 + d];
    wlW[idx] = s; return;
  }
  idx -= 1600;
  if (idx < 1024){ biasg[idx] = b_ih[idx] + b_hh[idx]; return; }
  idx -= 1024;
  if (idx < 262144){
    int p8 = __builtin_amdgcn_cvt_pk_fp8_f32(W_hh[idx], W_hh[idx], 0, false);
    whh8[idx] = (char)(p8 & 0xff);
    return;
  }
  idx -= 262144;
  if (idx < 229376){
    int n = idx / 224, k = idx % 224;
    wih[idx] = (k < 200) ? f2bf(W_ih[n*200 + k]) : (ushort_t)0;
    return;
  }
  idx -= 229376;
  if (idx < 102400){
    int l = idx / 512, c = idx % 512;
    wenc[idx] = f2bf(fcW[l*582 + 50 + c]); return;
  }
  idx -= 102400;
  if (idx < 44544){ combwb[idx] = f2bf(combW[idx]); return; }
}

// ---------- generic 64x64 bf16 MFMA GEMM: C[m,n] = sum_k A[m,k]*B[n,k] ----------
// Grid: x = N-tiles (fast dim), y = M-blocks.
// EPI 0: bf16 out [m][Nvalid]
// EPI 1: +bias, bf16 out in k_rec Gperm layout [t][blk32][w16][g4][u16][qd4]
// EPI 2: masked fp32 logits, m time-major -> out b-major [b*T+t][58]
template<int EPI>
__global__ __launch_bounds__(256) void k_gemm(
    const ushort_t* __restrict__ A, long lda,
    const ushort_t* __restrict__ Bm, int K, int Nvalid,
    void* __restrict__ Cout, const float* __restrict__ bias, const int* __restrict__ len){
  __shared__ __attribute__((aligned(16))) ushort_t As[64][48];
  __shared__ __attribute__((aligned(16))) ushort_t Bs[64][48];
  int tid  = threadIdx.x;
  int lane = tid & 63, wave = tid >> 6;
  int u = lane & 15, quad = lane >> 4;
  int mh = wave >> 1, nh = wave & 1;
  long m0 = (long)blockIdx.y * 64;
  int  n0 = blockIdx.x * 64;
  int lrow = tid >> 2;
  int lcol = (tid & 3) * 8;
  const ushort_t* Arow = A + (m0 + lrow) * lda + lcol;
  bool bvalid = (n0 + lrow) < Nvalid;
  const ushort_t* Brow = Bm + (long)(n0 + lrow) * K + lcol;
  floatx4 acc[2][2] = {};
  for (int k = 0; k < K; k += 32){
    short8 av = *(const short8*)(const void*)(Arow + k);
    short8 bv = {0,0,0,0,0,0,0,0};
    if (bvalid) bv = *(const short8*)(const void*)(Brow + k);
    __syncthreads();
    *(short8*)(void*)&As[lrow][lcol] = av;
    *(short8*)(void*)&Bs[lrow][lcol] = bv;
    __syncthreads();
    short8 a0 = *(const short8*)(const void*)&As[mh*32 + u][quad*8];
    short8 a1 = *(const short8*)(const void*)&As[mh*32 + 16 + u][quad*8];
    short8 b0 = *(const short8*)(const void*)&Bs[nh*32 + u][quad*8];
    short8 b1 = *(const short8*)(const void*)&Bs[nh*32 + 16 + u][quad*8];
    acc[0][0] = __builtin_amdgcn_mfma_f32_16x16x32_bf16(a0, b0, acc[0][0], 0, 0, 0);
    acc[0][1] = __builtin_amdgcn_mfma_f32_16x16x32_bf16(a0, b1, acc[0][1], 0, 0, 0);
    acc[1][0] = __builtin_amdgcn_mfma_f32_16x16x32_bf16(a1, b0, acc[1][0], 0, 0, 0);
    acc[1][1] = __builtin_amdgcn_mfma_f32_16x16x32_bf16(a1, b1, acc[1][1], 0, 0, 0);
  }
  if (EPI == 1){
    #pragma unroll
    for (int mi = 0; mi < 2; mi++){
      #pragma unroll
      for (int ni = 0; ni < 2; ni++){
        long mm = m0 + mh*32 + mi*16 + quad*4;     // 4 r's = 4 consecutive b (qd 0..3)
        int n = n0 + nh*32 + ni*16 + u;
        float bv = bias[n];
        int t = (int)(mm >> 7);
        int b = (int)(mm & 127);
        int blk = b >> 2;                           // b % 4 == 0 here
        int g = n >> 8, j = n & 255, ut = j & 15, jt = j >> 4;
        long idx = ((((long)t*32 + blk)*16 + jt)*4 + g)*64 + ut*4;
        short4v pk;
        #pragma unroll
        for (int r = 0; r < 4; r++) pk[r] = (short)f2bf(acc[mi][ni][r] + bv);
        *(short4v*)(void*)((ushort_t*)Cout + idx) = pk;
      }
    }
  } else {
    for (int mi = 0; mi < 2; mi++){
      for (int ni = 0; ni < 2; ni++){
        for (int r = 0; r < 4; r++){
          long m = m0 + mh*32 + mi*16 + quad*4 + r;
          int  n = n0 + nh*32 + ni*16 + u;
          float v = acc[mi][ni][r];
          if (EPI == 0){
            if (n < Nvalid) ((ushort_t*)Cout)[m * Nvalid + n] = f2bf(v);
          } else {
            if (n < Nvalid){
              int t = (int)(m >> 7); int b = (int)(m & 127);
              float o = (t < len[b]) ? v : 0.0f;
              if (t == 0 && n == 0) o = -1e30f;
              ((float*)Cout)[((long)b * T_ + t) * SP_ + n] = o;
            }
          }
        }
      }
    }
  }
}

// ---------- exclusive cumsum over t, in place on E (bf16, time-major rows) ----------
__global__ __launch_bounds__(256) void k_cum200(ushort_t* __restrict__ E){
  int b = blockIdx.x;
  int c = threadIdx.x;
  if (c >= LIN_) return;
  float acc = 0.f;
  ushort_t* p = E + (long)b * LIN_ + c;      // row (t*128+b)
  const long rs = (long)B_ * LIN_;           // per-t stride
  for (int t0 = 0; t0 < T_; t0 += 16){
    float vv[16];
    #pragma unroll
    for (int i = 0; i < 16; i++) vv[i] = bf2f(p[i*rs]);
    #pragma unroll
    for (int i = 0; i < 16; i++){ p[i*rs] = f2bf(acc); acc += vv[i]; }
    p += 16*rs;
  }
}

// ---------- z = tanh((CW[t]-CW[ls])*inv + posW + wlW + b), t=0 -> 0, pad K to 224 ----------
__global__ __launch_bounds__(256) void k_z(
    const ushort_t* __restrict__ CW, const int* __restrict__ ls, const int* __restrict__ lp,
    const int* __restrict__ wid, const float* __restrict__ inv,
    const float* __restrict__ posW, const float* __restrict__ wlW,
    const float* __restrict__ fcb, ushort_t* __restrict__ zbf){
  int m = blockIdx.x;               // time-major row t*128+b
  int l = threadIdx.x;
  if (l >= LINP_) return;
  int t = m >> 7;
  int b = m & 127;
  int ar = b * T_ + t;              // b-major aux index
  ushort_t o = 0;
  if (t != 0 && l < LIN_){
    int lsv = ls[ar];
    float x = bf2f(CW[(long)m * LIN_ + l]) - bf2f(CW[((long)lsv * B_ + b) * LIN_ + l]);
    x = x * inv[ar] + posW[lp[ar]*LIN_ + l] + wlW[wid[ar]*LIN_ + l] + fcb[l];
    o = f2bf(ftanh(x));
  }
  zbf[(long)m * LINP_ + l] = o;
}

// ---------- LSTM recurrence: 32 blocks x 1024 threads, NB=4 batches/block ----------
// THIS ROUND: (T5) s_setprio(1) around the MFMA cluster -- the 4 lockstep waves/SIMD
// have role diversity (one in MFMA burst while others run activation tails); priority
// keeps the matrix pipe dense. (balance) h ring deepened to 8 buffers; vbf dump now
// happens every 4th step with ALL 16 waves dumping one row each, instead of waves 0-3
// (one per SIMD) paying ~40cyc of dump VALU+store EVERY step that the barrier then
// charged to all waves.
__global__ __launch_bounds__(1024, 4) void k_rec(
    const ushort_t* __restrict__ Gperm, const char* __restrict__ whh8,
    ushort_t* __restrict__ vbf){
  int blk  = blockIdx.x;                      // 0..31: batches blk*4 .. blk*4+3
  int tid  = threadIdx.x;
  int lane = tid & 63, w = tid >> 6;          // w in [0,16): hidden j-tile
  int u = lane & 15, quad = lane >> 4;        // quad = local batch index
  // ring[s]: h(t) written at step t into ring[(t+1)&7]; read at step t+1 from ring[(t+1)&7]
  __shared__ __attribute__((aligned(16))) char h8[8][16][272];
  for (int i = tid; i < (int)(sizeof(h8)/4); i += 1024) ((int*)h8)[i] = 0;

  // W_hh fp8 B-fragments (MX K=128): gate g, cols w*16+u; pinned in VGPRs.
  intx8 wfx[4][2];
  #pragma unroll
  for (int g = 0; g < 4; g++){
    int grow = g*256 + w*16 + u;
    #pragma unroll
    for (int kc = 0; kc < 2; kc++){
      intx8 v = *(const intx8*)(const void*)(whh8 + (long)grow*256 + kc*128 + quad*32);
      asm volatile("" : "+v"(v));
      wfx[g][kc] = v;
    }
  }
  float c_reg = 0.f;
  floatx4 acc[4] = {};   // element 0 rebuilt each step; elements 1..3 stay 0 forever

  // dump assignment: wave w dumps step s = t-4+(w>>2), batch row w&3 (every 4th step)
  int dstep = w >> 2, drow = w & 3;

  // Gperm[t][blk][w][g][u][qd]: lane (quad,u) reads gate g at g*64 + u*4 + quad
  const ushort_t* gp0 = Gperm + ((long)blk*16 + w)*256 + (long)u*4 + quad;
  ushort_t gb[4];
  #pragma unroll
  for (int g = 0; g < 4; g++) gb[g] = gp0[g*64];

  for (int t = 0; t < T_; t++){
    #pragma unroll
    for (int g = 0; g < 4; g++) acc[g][0] = bf2f(gb[g]);
    // lgkm-only barrier: h8 write(t-1) -> read(t) edge; vbf stores + Gperm loads
    // stay in flight across the barrier (T4: never drain vmcnt in the loop).
    asm volatile("s_waitcnt lgkmcnt(0)\n\ts_barrier" ::: "memory");
    intx8 af0 = *(const intx8*)(const void*)&h8[t & 7][u][quad*32];
    intx8 af1 = *(const intx8*)(const void*)&h8[t & 7][u][128 + quad*32];
    // every 4th step: balanced vbf dump of h(t-4..t-1), one row per wave
    if ((t & 3) == 0 && t >= 4){
      int s = t - 4 + dstep;
      ushort_t* vrow = vbf + ((long)s * B_ + blk*4 + drow) * 768;
      uint32 p = *(const uint32*)(const void*)&h8[(s + 1) & 7][drow*4][lane*4];
      float2v lo = __builtin_amdgcn_cvt_pk_f32_fp8(p, false);
      float2v hi = __builtin_amdgcn_cvt_pk_f32_fp8(p, true);
      short4v pk;
      pk[0] = (short)f2bf(lo[0]); pk[1] = (short)f2bf(lo[1]);
      pk[2] = (short)f2bf(hi[0]); pk[3] = (short)f2bf(hi[1]);
      *(short4v*)(void*)&vrow[lane*4] = pk;
    }
    // EARLY: prefetch next Gperm values (hides HBM latency under MFMAs)
    if (t + 1 < T_){
      const ushort_t* gp = gp0 + (long)(t+1)*131072;
      #pragma unroll
      for (int g = 0; g < 4; g++) gb[g] = gp[g*64];
    }
    __builtin_amdgcn_s_setprio(1);
    // gates i,f
    acc[0] = __builtin_amdgcn_mfma_scale_f32_16x16x128_f8f6f4(
        af0, wfx[0][0], acc[0], 0, 0, 0, 0x7F7F7F7F, 0, 0x7F7F7F7F);
    acc[0] = __builtin_amdgcn_mfma_scale_f32_16x16x128_f8f6f4(
        af1, wfx[0][1], acc[0], 0, 0, 0, 0x7F7F7F7F, 0, 0x7F7F7F7F);
    acc[1] = __builtin_amdgcn_mfma_scale_f32_16x16x128_f8f6f4(
        af0, wfx[1][0], acc[1], 0, 0, 0, 0x7F7F7F7F, 0, 0x7F7F7F7F);
    acc[1] = __builtin_amdgcn_mfma_scale_f32_16x16x128_f8f6f4(
        af1, wfx[1][1], acc[1], 0, 0, 0, 0x7F7F7F7F, 0, 0x7F7F7F7F);
    // i,f activations co-issue on VALU while g,o MFMAs occupy the matrix pipe
    float iv = fsig (acc[0][0]);
    float fv = fsig (acc[1][0]);
    // gates g,o
    acc[2] = __builtin_amdgcn_mfma_scale_f32_16x16x128_f8f6f4(
        af0, wfx[2][0], acc[2], 0, 0, 0, 0x7F7F7F7F, 0, 0x7F7F7F7F);
    acc[2] = __builtin_amdgcn_mfma_scale_f32_16x16x128_f8f6f4(
        af1, wfx[2][1], acc[2], 0, 0, 0, 0x7F7F7F7F, 0, 0x7F7F7F7F);
    acc[3] = __builtin_amdgcn_mfma_scale_f32_16x16x128_f8f6f4(
        af0, wfx[3][0], acc[3], 0, 0, 0, 0x7F7F7F7F, 0, 0x7F7F7F7F);
    acc[3] = __builtin_amdgcn_mfma_scale_f32_16x16x128_f8f6f4(
        af1, wfx[3][1], acc[3], 0, 0, 0, 0x7F7F7F7F, 0, 0x7F7F7F7F);
    __builtin_amdgcn_s_setprio(0);
    float gv = ftanh(acc[2][0]);
    float ov = fsig (acc[3][0]);
    float c  = fv * c_reg + iv * gv;
    c_reg = c;
    float h  = ov * ftanh(c);
    int p8 = __builtin_amdgcn_cvt_pk_fp8_f32(h, h, 0, false);
    h8[(t+1)&7][quad*4][w*16 + u] = (char)(p8 & 0xff);
  }
  __syncthreads();
  // final dump: steps 508..511 (ring slots 5,6,7,0), one row per wave
  {
    int s = (T_ - 4) + dstep;
    ushort_t* vrow = vbf + ((long)s * B_ + blk*4 + drow) * 768;
    uint32 p = *(const uint32*)(const void*)&h8[(s + 1) & 7][drow*4][lane*4];
    float2v lo = __builtin_amdgcn_cvt_pk_f32_fp8(p, false);
    float2v hi = __builtin_amdgcn_cvt_pk_f32_fp8(p, true);
    short4v pk;
    pk[0] = (short)f2bf(lo[0]); pk[1] = (short)f2bf(lo[1]);
    pk[2] = (short)f2bf(hi[0]); pk[3] = (short)f2bf(hi[1]);
    *(short4v*)(void*)&vrow[lane*4] = pk;
  }
}

extern "C" void kernel_launch(void* const* d_in, const int* in_sizes, int n_in,
                              void* d_out, int out_size, void* d_ws, size_t ws_size,
                              hipStream_t stream){
  (void)in_sizes; (void)n_in; (void)out_size; (void)ws_size;
  const float* enc     = (const float*)d_in[0];
  const int*   sep     = (const int*)  d_in[1];
  const int*   pos_ids = (const int*)  d_in[2];
  const int*   len     = (const int*)  d_in[3];
  const float* pos_emb = (const float*)d_in[4];
  const float* wl_emb  = (const float*)d_in[5];
  const float* fcW     = (const float*)d_in[6];
  const float* fcb     = (const float*)d_in[7];
  const float* W_ih    = (const float*)d_in[8];
  const float* W_hh    = (const float*)d_in[9];
  const float* b_ih    = (const float*)d_in[10];
  const float* b_hh    = (const float*)d_in[11];
  const float* combW   = (const float*)d_in[12];

  char* ws = (char*)d_ws;
  int*      ls    = (int*)     (ws + OFF_LS);
  int*      lp    = (int*)     (ws + OFF_LP);
  int*      wid   = (int*)     (ws + OFF_WID);
  float*    inv   = (float*)   (ws + OFF_INV);
  float*    posW  = (float*)   (ws + OFF_POSW);
  float*    wlW   = (float*)   (ws + OFF_WLW);
  float*    biasg = (float*)   (ws + OFF_BIASG);
  char*     whh8  = (char*)    (ws + OFF_WHH);
  ushort_t* wih   = (ushort_t*)(ws + OFF_WIH);
  ushort_t* wenc  = (ushort_t*)(ws + OFF_WENC);
  ushort_t* combwb= (ushort_t*)(ws + OFF_COMBW);
  ushort_t* ecw   = (ushort_t*)(ws + OFF_ECW);
  ushort_t* zbf   = (ushort_t*)(ws + OFF_Z);
  ushort_t* gperm = (ushort_t*)(ws + OFF_GPERM);
  ushort_t* vbf   = (ushort_t*)(ws + OFF_VBF);

  k_scan<<<B_, 512, 0, stream>>>(sep, pos_ids, ls, lp, wid, inv);
  k_encbf<<<BT_, 256, 0, stream>>>(enc, vbf);
  k_small<<<2530, 256, 0, stream>>>(pos_emb, wl_emb, fcW, W_ih, W_hh, b_ih, b_hh, combW,
                                    posW, wlW, biasg, whh8, wih, wenc, combwb);
  // E = enc @ Wenc^T  (rows time-major)
  k_gemm<0><<<dim3(4, BT_/64), 256, 0, stream>>>(vbf + 256, 768L, wenc, 512, LIN_, ecw, nullptr, nullptr);
  // exclusive cumsum over t (in place) -> CW
  k_cum200<<<B_, 256, 0, stream>>>(ecw);
  // z = tanh(...)
  k_z<<<BT_, 256, 0, stream>>>(ecw, ls, lp, wid, inv, posW, wlW, fcb, zbf);
  // Gperm = z @ W_ih^T + biases, written in k_rec's [t][blk][w][g][u][qd] layout
  k_gemm<1><<<dim3(16, BT_/64), 256, 0, stream>>>(zbf, (long)LINP_, wih, LINP_, G4_, gperm, biasg, nullptr);
  // LSTM recurrence (32 blocks x 16 waves, setprio MFMA cluster + balanced dump ring)
  k_rec<<<32, 1024, 0, stream>>>(gperm, whh8, vbf);
  // logits = [hs, enc] @ combine_W^T, masked, scattered to b-major output
  k_gemm<2><<<dim3(1, BT_/64), 256, 0, stream>>>(vbf, 768L, combwb, 768, SP_, d_out, nullptr, len);
}

// Round 7
// 876.763 us; speedup vs baseline: 1.1951x; 1.0015x over previous
//
#include <hip/hip_runtime.h>

typedef unsigned short ushort_t;
typedef unsigned int uint32;
typedef __attribute__((ext_vector_type(8))) short short8;
typedef __attribute__((ext_vector_type(4))) short short4v;
typedef __attribute__((ext_vector_type(4))) float floatx4;
typedef __attribute__((ext_vector_type(2))) float float2v;
typedef __attribute__((ext_vector_type(8))) int intx8;

#define B_    128
#define T_    512
#define H_    256
#define H2_   512
#define LIN_  200
#define LINP_ 224
#define G4_   1024
#define SP_   58
#define BT_   (B_*T_)

// ---------- ws layout (bytes) ----------
#define OFF_LS     0UL          // int  [B,T]      262144
#define OFF_LP     262144UL     // int  [B,T]      262144
#define OFF_WID    524288UL     // int  [B,T]      262144
#define OFF_INV    786432UL     // f32  [B,T]      262144
#define OFF_POSW   1212416UL    // f32  [32][200]   25600
#define OFF_WLW    1238016UL    // f32  [8][200]     6400
#define OFF_BIASG  1244416UL    // f32  [1024]       4096
#define OFF_WHH    1248512UL    // fp8  [1024][256] 262144
#define OFF_WIH    1772800UL    // bf16 [1024][224] 458752
#define OFF_WENC   2231552UL    // bf16 [200][512]  204800
#define OFF_COMBW  2436352UL    // bf16 [58][768]    89088
#define OFF_ECW    2525440UL    // bf16 [65536][200] time-major rows (t*128+b)
#define OFF_Z      28739840UL   // bf16 [65536][224] time-major rows
#define OFF_GPERM  58099968UL   // bf16 swizzled [512][32 blk][16 w][4 g][16 u][4 qd]
#define OFF_VBF    192317696UL  // bf16 [65536][768] time-major rows (0:256 hs, 256:768 enc)

__device__ __forceinline__ ushort_t f2bf(float x){
  uint32 u = __float_as_uint(x);
  u += 0x7fffu + ((u >> 16) & 1u);
  return (ushort_t)(u >> 16);
}
__device__ __forceinline__ float bf2f(ushort_t v){
  return __uint_as_float(((uint32)v) << 16);
}
// fast sigmoid/tanh (exp2-based __expf + v_rcp); |err| ~1e-5, way inside bf16
__device__ __forceinline__ float fsig(float x){
  return __builtin_amdgcn_rcpf(1.0f + __expf(-x));
}
__device__ __forceinline__ float ftanh(float x){
  return 1.0f - 2.0f * __builtin_amdgcn_rcpf(1.0f + __expf(2.0f * x));
}

// ---------- scan: last_sep / wordlen / last_pos, parallel Hillis-Steele ----------
__global__ __launch_bounds__(512) void k_scan(const int* __restrict__ sep, const int* __restrict__ pos_ids,
                       int* __restrict__ ls, int* __restrict__ lp,
                       int* __restrict__ wid, float* __restrict__ inv){
  int b = blockIdx.x, t = threadIdx.x;
  __shared__ int sm[512];
  int v = (sep[b*T_ + t] > 0) ? t : 0;
  sm[t] = v;
  __syncthreads();
  #pragma unroll
  for (int off = 1; off < 512; off <<= 1){
    int o = (t >= off) ? sm[t - off] : 0;
    __syncthreads();
    v = (o > v) ? o : v;
    sm[t] = v;
    __syncthreads();
  }
  int l = (t == 0) ? 0 : sm[t - 1];      // last sep strictly before t
  int wlen = t - l;
  int wsv  = (wlen < 1) ? 1 : wlen;
  ls[b*T_ + t]  = l;
  lp[b*T_ + t]  = pos_ids[b*T_ + l];
  wid[b*T_ + t] = (wsv > 7) ? 7 : wsv;
  inv[b*T_ + t] = 1.0f / (float)wsv;
}

// ---------- enc -> bf16 into vbf[t*128+b][256:768] ----------
// grid-stride, float4 loads + packed bf16x4 stores (old version: 65536 one-row
// workgroups of 2 scalar loads each -> ~100us of pure dispatch overhead)
__global__ __launch_bounds__(256) void k_encbf(const float* __restrict__ enc, ushort_t* __restrict__ vbf){
  const long total = (long)BT_ * 128;          // float4 count (65536 rows x 128)
  for (long i = (long)blockIdx.x * 256 + threadIdx.x; i < total; i += 2048L * 256){
    floatx4 v = ((const floatx4*)enc)[i];
    long row = i >> 7;                         // b*512 + t (enc layout)
    int c4 = (int)(i & 127);
    int b = (int)(row >> 9), t = (int)(row & (T_-1));
    short4v pk;
    pk[0] = (short)f2bf(v[0]); pk[1] = (short)f2bf(v[1]);
    pk[2] = (short)f2bf(v[2]); pk[3] = (short)f2bf(v[3]);
    *(short4v*)(void*)(vbf + ((long)t * B_ + b) * 768 + 256 + c4*4) = pk;
  }
}

// ---------- small precomputes / weight conversions ----------
__global__ __launch_bounds__(256) void k_small(
    const float* __restrict__ pos_emb, const float* __restrict__ wl_emb,
    const float* __restrict__ fcW, const float* __restrict__ W_ih,
    const float* __restrict__ W_hh, const float* __restrict__ b_ih,
    const float* __restrict__ b_hh, const float* __restrict__ combW,
    float* __restrict__ posW, float* __restrict__ wlW, float* __restrict__ biasg,
    char* __restrict__ whh8, ushort_t* __restrict__ wih,
    ushort_t* __restrict__ wenc, ushort_t* __restrict__ combwb){
  int idx = blockIdx.x * 256 + threadIdx.x;
  if (idx < 6400){
    int p = idx / 200, l = idx % 200;
    float s = 0.f;
    for (int d = 0; d < 50; d++) s += pos_emb[p*50 + d] * fcW[l*582 + d];
    posW[idx] = s; return;
  }
  idx -= 6400;
  if (idx < 1600){
    int w = idx / 200, l = idx % 200;
    float s = 0.f;
    for (int d = 0; d < 20; d++) s += wl_emb[w*20 + d] * fcW[l*582 + 562 + d];
    wlW[idx] = s; return;
  }
  idx -= 1600;
  if (idx < 1024){ biasg[idx] = b_ih[idx] + b_hh[idx]; return; }
  idx -= 1024;
  if (idx < 262144){
    int p8 = __builtin_amdgcn_cvt_pk_fp8_f32(W_hh[idx], W_hh[idx], 0, false);
    whh8[idx] = (char)(p8 & 0xff);
    return;
  }
  idx -= 262144;
  if (idx < 229376){
    int n = idx / 224, k = idx % 224;
    wih[idx] = (k < 200) ? f2bf(W_ih[n*200 + k]) : (ushort_t)0;
    return;
  }
  idx -= 229376;
  if (idx < 102400){
    int l = idx / 512, c = idx % 512;
    wenc[idx] = f2bf(fcW[l*582 + 50 + c]); return;
  }
  idx -= 102400;
  if (idx < 44544){ combwb[idx] = f2bf(combW[idx]); return; }
}

// ---------- generic 64x64 bf16 MFMA GEMM: C[m,n] = sum_k A[m,k]*B[n,k] ----------
// Grid: x = N-tiles (fast dim), y = M-blocks.
// EPI 0: bf16 out [m][Nvalid]
// EPI 1: +bias, bf16 out in k_rec Gperm layout [t][blk32][w16][g4][u16][qd4]
// EPI 2: masked fp32 logits, m time-major -> out b-major [b*T+t][58]
template<int EPI>
__global__ __launch_bounds__(256) void k_gemm(
    const ushort_t* __restrict__ A, long lda,
    const ushort_t* __restrict__ Bm, int K, int Nvalid,
    void* __restrict__ Cout, const float* __restrict__ bias, const int* __restrict__ len){
  __shared__ __attribute__((aligned(16))) ushort_t As[64][48];
  __shared__ __attribute__((aligned(16))) ushort_t Bs[64][48];
  int tid  = threadIdx.x;
  int lane = tid & 63, wave = tid >> 6;
  int u = lane & 15, quad = lane >> 4;
  int mh = wave >> 1, nh = wave & 1;
  long m0 = (long)blockIdx.y * 64;
  int  n0 = blockIdx.x * 64;
  int lrow = tid >> 2;
  int lcol = (tid & 3) * 8;
  const ushort_t* Arow = A + (m0 + lrow) * lda + lcol;
  bool bvalid = (n0 + lrow) < Nvalid;
  const ushort_t* Brow = Bm + (long)(n0 + lrow) * K + lcol;
  floatx4 acc[2][2] = {};
  for (int k = 0; k < K; k += 32){
    short8 av = *(const short8*)(const void*)(Arow + k);
    short8 bv = {0,0,0,0,0,0,0,0};
    if (bvalid) bv = *(const short8*)(const void*)(Brow + k);
    __syncthreads();
    *(short8*)(void*)&As[lrow][lcol] = av;
    *(short8*)(void*)&Bs[lrow][lcol] = bv;
    __syncthreads();
    short8 a0 = *(const short8*)(const void*)&As[mh*32 + u][quad*8];
    short8 a1 = *(const short8*)(const void*)&As[mh*32 + 16 + u][quad*8];
    short8 b0 = *(const short8*)(const void*)&Bs[nh*32 + u][quad*8];
    short8 b1 = *(const short8*)(const void*)&Bs[nh*32 + 16 + u][quad*8];
    acc[0][0] = __builtin_amdgcn_mfma_f32_16x16x32_bf16(a0, b0, acc[0][0], 0, 0, 0);
    acc[0][1] = __builtin_amdgcn_mfma_f32_16x16x32_bf16(a0, b1, acc[0][1], 0, 0, 0);
    acc[1][0] = __builtin_amdgcn_mfma_f32_16x16x32_bf16(a1, b0, acc[1][0], 0, 0, 0);
    acc[1][1] = __builtin_amdgcn_mfma_f32_16x16x32_bf16(a1, b1, acc[1][1], 0, 0, 0);
  }
  if (EPI == 1){
    #pragma unroll
    for (int mi = 0; mi < 2; mi++){
      #pragma unroll
      for (int ni = 0; ni < 2; ni++){
        long mm = m0 + mh*32 + mi*16 + quad*4;     // 4 r's = 4 consecutive b (qd 0..3)
        int n = n0 + nh*32 + ni*16 + u;
        float bv = bias[n];
        int t = (int)(mm >> 7);
        int b = (int)(mm & 127);
        int blk = b >> 2;                           // b % 4 == 0 here
        int g = n >> 8, j = n & 255, ut = j & 15, jt = j >> 4;
        long idx = ((((long)t*32 + blk)*16 + jt)*4 + g)*64 + ut*4;
        short4v pk;
        #pragma unroll
        for (int r = 0; r < 4; r++) pk[r] = (short)f2bf(acc[mi][ni][r] + bv);
        *(short4v*)(void*)((ushort_t*)Cout + idx) = pk;
      }
    }
  } else {
    for (int mi = 0; mi < 2; mi++){
      for (int ni = 0; ni < 2; ni++){
        for (int r = 0; r < 4; r++){
          long m = m0 + mh*32 + mi*16 + quad*4 + r;
          int  n = n0 + nh*32 + ni*16 + u;
          float v = acc[mi][ni][r];
          if (EPI == 0){
            if (n < Nvalid) ((ushort_t*)Cout)[m * Nvalid + n] = f2bf(v);
          } else {
            if (n < Nvalid){
              int t = (int)(m >> 7); int b = (int)(m & 127);
              float o = (t < len[b]) ? v : 0.0f;
              if (t == 0 && n == 0) o = -1e30f;
              ((float*)Cout)[((long)b * T_ + t) * SP_ + n] = o;
            }
          }
        }
      }
    }
  }
}

// ---------- exclusive cumsum over t, in place on E (bf16, time-major rows) ----------
__global__ __launch_bounds__(256) void k_cum200(ushort_t* __restrict__ E){
  int b = blockIdx.x;
  int c = threadIdx.x;
  if (c >= LIN_) return;
  float acc = 0.f;
  ushort_t* p = E + (long)b * LIN_ + c;      // row (t*128+b)
  const long rs = (long)B_ * LIN_;           // per-t stride
  for (int t0 = 0; t0 < T_; t0 += 16){
    float vv[16];
    #pragma unroll
    for (int i = 0; i < 16; i++) vv[i] = bf2f(p[i*rs]);
    #pragma unroll
    for (int i = 0; i < 16; i++){ p[i*rs] = f2bf(acc); acc += vv[i]; }
    p += 16*rs;
  }
}

// ---------- z = tanh((CW[t]-CW[ls])*inv + posW + wlW + b), t=0 -> 0, pad K to 224 ----------
// 8 rows per block (old: 65536 one-row workgroups -> dispatch overhead)
__global__ __launch_bounds__(256) void k_z(
    const ushort_t* __restrict__ CW, const int* __restrict__ ls, const int* __restrict__ lp,
    const int* __restrict__ wid, const float* __restrict__ inv,
    const float* __restrict__ posW, const float* __restrict__ wlW,
    const float* __restrict__ fcb, ushort_t* __restrict__ zbf){
  int l = threadIdx.x;
  if (l >= LINP_) return;
  float fb = (l < LIN_) ? fcb[l] : 0.f;
  #pragma unroll
  for (int i = 0; i < 8; i++){
    int m = blockIdx.x * 8 + i;       // time-major row t*128+b
    int t = m >> 7;
    int b = m & 127;
    int ar = b * T_ + t;              // b-major aux index
    ushort_t o = 0;
    if (t != 0 && l < LIN_){
      int lsv = ls[ar];
      float x = bf2f(CW[(long)m * LIN_ + l]) - bf2f(CW[((long)lsv * B_ + b) * LIN_ + l]);
      x = x * inv[ar] + posW[lp[ar]*LIN_ + l] + wlW[wid[ar]*LIN_ + l] + fb;
      o = f2bf(ftanh(x));
    }
    zbf[(long)m * LINP_ + l] = o;
  }
}

// ---------- LSTM recurrence: 32 blocks x 1024 threads, NB=4 batches/block ----------
// Round-5 plateau form (439us): lgkm-only barrier, early dump/prefetch, interleaved
// activations. Scheduling levers beyond this (setprio, dump ring, packed h4, full
// syncthreads) all measured neutral-to-worse; per-step budget = 1104cyc MFMA issue
// (shape-invariant) + dependency-forced tails. Structural plateau for this decomp.
__global__ __launch_bounds__(1024, 4) void k_rec(
    const ushort_t* __restrict__ Gperm, const char* __restrict__ whh8,
    ushort_t* __restrict__ vbf){
  int blk  = blockIdx.x;                      // 0..31: batches blk*4 .. blk*4+3
  int tid  = threadIdx.x;
  int lane = tid & 63, w = tid >> 6;          // w in [0,16): hidden j-tile
  int u = lane & 15, quad = lane >> 4;        // quad = local batch index
  __shared__ __attribute__((aligned(16))) char h8[2][16][272];   // row stride 272
  for (int i = tid; i < (int)(sizeof(h8)/4); i += 1024) ((int*)h8)[i] = 0;

  // W_hh fp8 B-fragments (MX K=128): gate g, cols w*16+u; pinned in VGPRs.
  intx8 wfx[4][2];
  #pragma unroll
  for (int g = 0; g < 4; g++){
    int grow = g*256 + w*16 + u;
    #pragma unroll
    for (int kc = 0; kc < 2; kc++){
      intx8 v = *(const intx8*)(const void*)(whh8 + (long)grow*256 + kc*128 + quad*32);
      asm volatile("" : "+v"(v));
      wfx[g][kc] = v;
    }
  }
  float c_reg = 0.f;
  floatx4 acc[4] = {};   // element 0 rebuilt each step; elements 1..3 stay 0 forever

  // Gperm[t][blk][w][g][u][qd]: lane (quad,u) reads gate g at g*64 + u*4 + quad
  const ushort_t* gp0 = Gperm + ((long)blk*16 + w)*256 + (long)u*4 + quad;
  ushort_t gb[4];
  #pragma unroll
  for (int g = 0; g < 4; g++) gb[g] = gp0[g*64];

  for (int t = 0; t < T_; t++){
    #pragma unroll
    for (int g = 0; g < 4; g++) acc[g][0] = bf2f(gb[g]);
    // lgkm-only barrier: h8 write(t-1) -> read(t) edge; vbf store + Gperm loads
    // stay in flight across the barrier (T4: never drain vmcnt in the loop).
    asm volatile("s_waitcnt lgkmcnt(0)\n\ts_barrier" ::: "memory");
    intx8 af0 = *(const intx8*)(const void*)&h8[t & 1][u][quad*32];
    intx8 af1 = *(const intx8*)(const void*)&h8[t & 1][u][128 + quad*32];
    // EARLY: coalesced vbf dump of h(t-1) (independent of MFMAs; VMEM pipe)
    if (t && w < 4){
      ushort_t* vrow = vbf + ((long)(t-1) * B_ + blk*4 + w) * 768;
      uint32 p = *(const uint32*)(const void*)&h8[t & 1][4*w][lane*4];
      float2v lo = __builtin_amdgcn_cvt_pk_f32_fp8(p, false);
      float2v hi = __builtin_amdgcn_cvt_pk_f32_fp8(p, true);
      short4v pk;
      pk[0] = (short)f2bf(lo[0]); pk[1] = (short)f2bf(lo[1]);
      pk[2] = (short)f2bf(hi[0]); pk[3] = (short)f2bf(hi[1]);
      *(short4v*)(void*)&vrow[lane*4] = pk;
    }
    // EARLY: prefetch next Gperm values (hides HBM latency under MFMAs)
    if (t + 1 < T_){
      const ushort_t* gp = gp0 + (long)(t+1)*131072;
      #pragma unroll
      for (int g = 0; g < 4; g++) gb[g] = gp[g*64];
    }
    // gates i,f
    acc[0] = __builtin_amdgcn_mfma_scale_f32_16x16x128_f8f6f4(
        af0, wfx[0][0], acc[0], 0, 0, 0, 0x7F7F7F7F, 0, 0x7F7F7F7F);
    acc[0] = __builtin_amdgcn_mfma_scale_f32_16x16x128_f8f6f4(
        af1, wfx[0][1], acc[0], 0, 0, 0, 0x7F7F7F7F, 0, 0x7F7F7F7F);
    acc[1] = __builtin_amdgcn_mfma_scale_f32_16x16x128_f8f6f4(
        af0, wfx[1][0], acc[1], 0, 0, 0, 0x7F7F7F7F, 0, 0x7F7F7F7F);
    acc[1] = __builtin_amdgcn_mfma_scale_f32_16x16x128_f8f6f4(
        af1, wfx[1][1], acc[1], 0, 0, 0, 0x7F7F7F7F, 0, 0x7F7F7F7F);
    // i,f activations co-issue on VALU while g,o MFMAs occupy the matrix pipe
    float iv = fsig (acc[0][0]);
    float fv = fsig (acc[1][0]);
    // gates g,o
    acc[2] = __builtin_amdgcn_mfma_scale_f32_16x16x128_f8f6f4(
        af0, wfx[2][0], acc[2], 0, 0, 0, 0x7F7F7F7F, 0, 0x7F7F7F7F);
    acc[2] = __builtin_amdgcn_mfma_scale_f32_16x16x128_f8f6f4(
        af1, wfx[2][1], acc[2], 0, 0, 0, 0x7F7F7F7F, 0, 0x7F7F7F7F);
    acc[3] = __builtin_amdgcn_mfma_scale_f32_16x16x128_f8f6f4(
        af0, wfx[3][0], acc[3], 0, 0, 0, 0x7F7F7F7F, 0, 0x7F7F7F7F);
    acc[3] = __builtin_amdgcn_mfma_scale_f32_16x16x128_f8f6f4(
        af1, wfx[3][1], acc[3], 0, 0, 0, 0x7F7F7F7F, 0, 0x7F7F7F7F);
    float gv = ftanh(acc[2][0]);
    float ov = fsig (acc[3][0]);
    float c  = fv * c_reg + iv * gv;
    c_reg = c;
    float h  = ov * ftanh(c);
    int p8 = __builtin_amdgcn_cvt_pk_fp8_f32(h, h, 0, false);
    h8[(t+1)&1][quad*4][w*16 + u] = (char)(p8 & 0xff);
  }
  __syncthreads();
  // final dump: h(511) lives in h8[0]
  if (w < 4){
    ushort_t* vrow = vbf + ((long)(T_-1) * B_ + blk*4 + w) * 768;
    uint32 p = *(const uint32*)(const void*)&h8[0][4*w][lane*4];
    float2v lo = __builtin_amdgcn_cvt_pk_f32_fp8(p, false);
    float2v hi = __builtin_amdgcn_cvt_pk_f32_fp8(p, true);
    short4v pk;
    pk[0] = (short)f2bf(lo[0]); pk[1] = (short)f2bf(lo[1]);
    pk[2] = (short)f2bf(hi[0]); pk[3] = (short)f2bf(hi[1]);
    *(short4v*)(void*)&vrow[lane*4] = pk;
  }
}

extern "C" void kernel_launch(void* const* d_in, const int* in_sizes, int n_in,
                              void* d_out, int out_size, void* d_ws, size_t ws_size,
                              hipStream_t stream){
  (void)in_sizes; (void)n_in; (void)out_size; (void)ws_size;
  const float* enc     = (const float*)d_in[0];
  const int*   sep     = (const int*)  d_in[1];
  const int*   pos_ids = (const int*)  d_in[2];
  const int*   len     = (const int*)  d_in[3];
  const float* pos_emb = (const float*)d_in[4];
  const float* wl_emb  = (const float*)d_in[5];
  const float* fcW     = (const float*)d_in[6];
  const float* fcb     = (const float*)d_in[7];
  const float* W_ih    = (const float*)d_in[8];
  const float* W_hh    = (const float*)d_in[9];
  const float* b_ih    = (const float*)d_in[10];
  const float* b_hh    = (const float*)d_in[11];
  const float* combW   = (const float*)d_in[12];

  char* ws = (char*)d_ws;
  int*      ls    = (int*)     (ws + OFF_LS);
  int*      lp    = (int*)     (ws + OFF_LP);
  int*      wid   = (int*)     (ws + OFF_WID);
  float*    inv   = (float*)   (ws + OFF_INV);
  float*    posW  = (float*)   (ws + OFF_POSW);
  float*    wlW   = (float*)   (ws + OFF_WLW);
  float*    biasg = (float*)   (ws + OFF_BIASG);
  char*     whh8  = (char*)    (ws + OFF_WHH);
  ushort_t* wih   = (ushort_t*)(ws + OFF_WIH);
  ushort_t* wenc  = (ushort_t*)(ws + OFF_WENC);
  ushort_t* combwb= (ushort_t*)(ws + OFF_COMBW);
  ushort_t* ecw   = (ushort_t*)(ws + OFF_ECW);
  ushort_t* zbf   = (ushort_t*)(ws + OFF_Z);
  ushort_t* gperm = (ushort_t*)(ws + OFF_GPERM);
  ushort_t* vbf   = (ushort_t*)(ws + OFF_VBF);

  k_scan<<<B_, 512, 0, stream>>>(sep, pos_ids, ls, lp, wid, inv);
  k_encbf<<<2048, 256, 0, stream>>>(enc, vbf);
  k_small<<<2530, 256, 0, stream>>>(pos_emb, wl_emb, fcW, W_ih, W_hh, b_ih, b_hh, combW,
                                    posW, wlW, biasg, whh8, wih, wenc, combwb);
  // E = enc @ Wenc^T  (rows time-major)
  k_gemm<0><<<dim3(4, BT_/64), 256, 0, stream>>>(vbf + 256, 768L, wenc, 512, LIN_, ecw, nullptr, nullptr);
  // exclusive cumsum over t (in place) -> CW
  k_cum200<<<B_, 256, 0, stream>>>(ecw);
  // z = tanh(...) (8 rows per block)
  k_z<<<BT_/8, 256, 0, stream>>>(ecw, ls, lp, wid, inv, posW, wlW, fcb, zbf);
  // Gperm = z @ W_ih^T + biases, written in k_rec's [t][blk][w][g][u][qd] layout
  k_gemm<1><<<dim3(16, BT_/64), 256, 0, stream>>>(zbf, (long)LINP_, wih, LINP_, G4_, gperm, biasg, nullptr);
  // LSTM recurrence (round-5 plateau form)
  k_rec<<<32, 1024, 0, stream>>>(gperm, whh8, vbf);
  // logits = [hs, enc] @ combine_W^T, masked, scattered to b-major output
  k_gemm<2><<<dim3(1, BT_/64), 256, 0, stream>>>(vbf, 768L, combwb, 768, SP_, d_out, nullptr, len);
}

// Round 8
// 871.805 us; speedup vs baseline: 1.2019x; 1.0057x over previous
//
#include <hip/hip_runtime.h>

typedef unsigned short ushort_t;
typedef unsigned int uint32;
typedef __attribute__((ext_vector_type(8))) short short8;
typedef __attribute__((ext_vector_type(4))) short short4v;
typedef __attribute__((ext_vector_type(4))) float floatx4;
typedef __attribute__((ext_vector_type(2))) float float2v;
typedef __attribute__((ext_vector_type(8))) int intx8;

#define B_    128
#define T_    512
#define H_    256
#define H2_   512
#define LIN_  200
#define LINP_ 224
#define G4_   1024
#define SP_   58
#define BT_   (B_*T_)

// ---------- ws layout (bytes) ----------
#define OFF_LS     0UL          // int  [B,T]      262144
#define OFF_LP     262144UL     // int  [B,T]      262144
#define OFF_WID    524288UL     // int  [B,T]      262144
#define OFF_INV    786432UL     // f32  [B,T]      262144
#define OFF_POSW   1212416UL    // f32  [32][200]   25600
#define OFF_WLW    1238016UL    // f32  [8][200]     6400
#define OFF_BIASG  1244416UL    // f32  [1024]       4096
#define OFF_WHH    1248512UL    // fp8  [1024][256] 262144
#define OFF_WIH    1772800UL    // bf16 [1024][224] 458752
#define OFF_WENC   2231552UL    // bf16 [200][512]  204800
#define OFF_COMBW  2436352UL    // bf16 [58][768]    89088
#define OFF_ECW    2525440UL    // bf16 [65536][200] time-major rows (t*128+b)
#define OFF_Z      28739840UL   // bf16 [65536][224] time-major rows
#define OFF_GPERM  58099968UL   // bf16 swizzled [512][32 blk][16 w][4 g][16 u][4 qd]
#define OFF_VBF    192317696UL  // bf16 [65536][768] time-major rows (0:256 hs, 256:768 enc)

__device__ __forceinline__ ushort_t f2bf(float x){
  uint32 u = __float_as_uint(x);
  u += 0x7fffu + ((u >> 16) & 1u);
  return (ushort_t)(u >> 16);
}
__device__ __forceinline__ float bf2f(ushort_t v){
  return __uint_as_float(((uint32)v) << 16);
}
// fast sigmoid/tanh (exp2-based __expf + v_rcp); |err| ~1e-5, way inside bf16
__device__ __forceinline__ float fsig(float x){
  return __builtin_amdgcn_rcpf(1.0f + __expf(-x));
}
__device__ __forceinline__ float ftanh(float x){
  return 1.0f - 2.0f * __builtin_amdgcn_rcpf(1.0f + __expf(2.0f * x));
}

// ---------- scan: last_sep / wordlen / last_pos, parallel Hillis-Steele ----------
__global__ __launch_bounds__(512) void k_scan(const int* __restrict__ sep, const int* __restrict__ pos_ids,
                       int* __restrict__ ls, int* __restrict__ lp,
                       int* __restrict__ wid, float* __restrict__ inv){
  int b = blockIdx.x, t = threadIdx.x;
  __shared__ int sm[512];
  int v = (sep[b*T_ + t] > 0) ? t : 0;
  sm[t] = v;
  __syncthreads();
  #pragma unroll
  for (int off = 1; off < 512; off <<= 1){
    int o = (t >= off) ? sm[t - off] : 0;
    __syncthreads();
    v = (o > v) ? o : v;
    sm[t] = v;
    __syncthreads();
  }
  int l = (t == 0) ? 0 : sm[t - 1];      // last sep strictly before t
  int wlen = t - l;
  int wsv  = (wlen < 1) ? 1 : wlen;
  ls[b*T_ + t]  = l;
  lp[b*T_ + t]  = pos_ids[b*T_ + l];
  wid[b*T_ + t] = (wsv > 7) ? 7 : wsv;
  inv[b*T_ + t] = 1.0f / (float)wsv;
}

// ---------- enc -> bf16 into vbf[t*128+b][256:768] ----------
__global__ __launch_bounds__(256) void k_encbf(const float* __restrict__ enc, ushort_t* __restrict__ vbf){
  const long total = (long)BT_ * 128;          // float4 count (65536 rows x 128)
  for (long i = (long)blockIdx.x * 256 + threadIdx.x; i < total; i += 2048L * 256){
    floatx4 v = ((const floatx4*)enc)[i];
    long row = i >> 7;                         // b*512 + t (enc layout)
    int c4 = (int)(i & 127);
    int b = (int)(row >> 9), t = (int)(row & (T_-1));
    short4v pk;
    pk[0] = (short)f2bf(v[0]); pk[1] = (short)f2bf(v[1]);
    pk[2] = (short)f2bf(v[2]); pk[3] = (short)f2bf(v[3]);
    *(short4v*)(void*)(vbf + ((long)t * B_ + b) * 768 + 256 + c4*4) = pk;
  }
}

// ---------- small precomputes / weight conversions ----------
__global__ __launch_bounds__(256) void k_small(
    const float* __restrict__ pos_emb, const float* __restrict__ wl_emb,
    const float* __restrict__ fcW, const float* __restrict__ W_ih,
    const float* __restrict__ W_hh, const float* __restrict__ b_ih,
    const float* __restrict__ b_hh, const float* __restrict__ combW,
    float* __restrict__ posW, float* __restrict__ wlW, float* __restrict__ biasg,
    char* __restrict__ whh8, ushort_t* __restrict__ wih,
    ushort_t* __restrict__ wenc, ushort_t* __restrict__ combwb){
  int idx = blockIdx.x * 256 + threadIdx.x;
  if (idx < 6400){
    int p = idx / 200, l = idx % 200;
    float s = 0.f;
    for (int d = 0; d < 50; d++) s += pos_emb[p*50 + d] * fcW[l*582 + d];
    posW[idx] = s; return;
  }
  idx -= 6400;
  if (idx < 1600){
    int w = idx / 200, l = idx % 200;
    float s = 0.f;
    for (int d = 0; d < 20; d++) s += wl_emb[w*20 + d] * fcW[l*582 + 562 + d];
    wlW[idx] = s; return;
  }
  idx -= 1600;
  if (idx < 1024){ biasg[idx] = b_ih[idx] + b_hh[idx]; return; }
  idx -= 1024;
  if (idx < 262144){
    int p8 = __builtin_amdgcn_cvt_pk_fp8_f32(W_hh[idx], W_hh[idx], 0, false);
    whh8[idx] = (char)(p8 & 0xff);
    return;
  }
  idx -= 262144;
  if (idx < 229376){
    int n = idx / 224, k = idx % 224;
    wih[idx] = (k < 200) ? f2bf(W_ih[n*200 + k]) : (ushort_t)0;
    return;
  }
  idx -= 229376;
  if (idx < 102400){
    int l = idx / 512, c = idx % 512;
    wenc[idx] = f2bf(fcW[l*582 + 50 + c]); return;
  }
  idx -= 102400;
  if (idx < 44544){ combwb[idx] = f2bf(combW[idx]); return; }
}

// ---------- generic 64x64 bf16 MFMA GEMM (kept for gemm<0>/<2>, ragged N) ----------
template<int EPI>
__global__ __launch_bounds__(256) void k_gemm(
    const ushort_t* __restrict__ A, long lda,
    const ushort_t* __restrict__ Bm, int K, int Nvalid,
    void* __restrict__ Cout, const float* __restrict__ bias, const int* __restrict__ len){
  __shared__ __attribute__((aligned(16))) ushort_t As[64][48];
  __shared__ __attribute__((aligned(16))) ushort_t Bs[64][48];
  int tid  = threadIdx.x;
  int lane = tid & 63, wave = tid >> 6;
  int u = lane & 15, quad = lane >> 4;
  int mh = wave >> 1, nh = wave & 1;
  long m0 = (long)blockIdx.y * 64;
  int  n0 = blockIdx.x * 64;
  int lrow = tid >> 2;
  int lcol = (tid & 3) * 8;
  const ushort_t* Arow = A + (m0 + lrow) * lda + lcol;
  bool bvalid = (n0 + lrow) < Nvalid;
  const ushort_t* Brow = Bm + (long)(n0 + lrow) * K + lcol;
  floatx4 acc[2][2] = {};
  for (int k = 0; k < K; k += 32){
    short8 av = *(const short8*)(const void*)(Arow + k);
    short8 bv = {0,0,0,0,0,0,0,0};
    if (bvalid) bv = *(const short8*)(const void*)(Brow + k);
    __syncthreads();
    *(short8*)(void*)&As[lrow][lcol] = av;
    *(short8*)(void*)&Bs[lrow][lcol] = bv;
    __syncthreads();
    short8 a0 = *(const short8*)(const void*)&As[mh*32 + u][quad*8];
    short8 a1 = *(const short8*)(const void*)&As[mh*32 + 16 + u][quad*8];
    short8 b0 = *(const short8*)(const void*)&Bs[nh*32 + u][quad*8];
    short8 b1 = *(const short8*)(const void*)&Bs[nh*32 + 16 + u][quad*8];
    acc[0][0] = __builtin_amdgcn_mfma_f32_16x16x32_bf16(a0, b0, acc[0][0], 0, 0, 0);
    acc[0][1] = __builtin_amdgcn_mfma_f32_16x16x32_bf16(a0, b1, acc[0][1], 0, 0, 0);
    acc[1][0] = __builtin_amdgcn_mfma_f32_16x16x32_bf16(a1, b0, acc[1][0], 0, 0, 0);
    acc[1][1] = __builtin_amdgcn_mfma_f32_16x16x32_bf16(a1, b1, acc[1][1], 0, 0, 0);
  }
  for (int mi = 0; mi < 2; mi++){
    for (int ni = 0; ni < 2; ni++){
      for (int r = 0; r < 4; r++){
        long m = m0 + mh*32 + mi*16 + quad*4 + r;
        int  n = n0 + nh*32 + ni*16 + u;
        float v = acc[mi][ni][r];
        if (EPI == 0){
          if (n < Nvalid) ((ushort_t*)Cout)[m * Nvalid + n] = f2bf(v);
        } else {
          if (n < Nvalid){
            int t = (int)(m >> 7); int b = (int)(m & 127);
            float o = (t < len[b]) ? v : 0.0f;
            if (t == 0 && n == 0) o = -1e30f;
            ((float*)Cout)[((long)b * T_ + t) * SP_ + n] = o;
          }
        }
      }
    }
  }
}

// ---------- 128x128 bf16 MFMA GEMM for Gperm (M=65536, N=1024, K=224) ----------
// m97 structure: 4 waves 2x2, acc[4][4]/wave, linear LDS [128][32], staged via
// global_load_lds width=16 (wave-uniform dst chunk, per-lane src), 2 barriers +
// 8 ds_read_b128 + 16 MFMA per wave per K-step. Epilogue: +bias, Gperm swizzle.
__global__ __launch_bounds__(256) void k_g128(
    const ushort_t* __restrict__ A,          // zbf [65536][224]
    const ushort_t* __restrict__ Bm,         // wih [1024][224]
    ushort_t* __restrict__ Cout, const float* __restrict__ bias){
  __shared__ __attribute__((aligned(16))) ushort_t As[128][32];
  __shared__ __attribute__((aligned(16))) ushort_t Bs[128][32];
  int tid  = threadIdx.x;
  int lane = tid & 63, w = tid >> 6;          // 4 waves
  int u = lane & 15, quad = lane >> 4;
  int wm = w >> 1, wn = w & 1;
  long m0 = (long)blockIdx.y * 128;
  int  n0 = blockIdx.x * 128;
  int srow = lane >> 2;                        // row-in-chunk
  int scol = (lane & 3) * 8;                   // k-offset (elems)
  floatx4 acc[4][4] = {};
  for (int k = 0; k < LINP_; k += 32){
    __syncthreads();                           // prev iter's LDS reads done
    #pragma unroll
    for (int c = 0; c < 2; c++){
      int ch = w + c*4;                        // chunk 0..7 (16 rows each)
      const ushort_t* sa = A + (m0 + ch*16 + srow) * (long)LINP_ + k + scol;
      __builtin_amdgcn_global_load_lds(
          (const __attribute__((address_space(1))) void*)sa,
          (__attribute__((address_space(3))) void*)((char*)&As[0][0] + ch*1024),
          16, 0, 0);
      const ushort_t* sb = Bm + (long)(n0 + ch*16 + srow) * LINP_ + k + scol;
      __builtin_amdgcn_global_load_lds(
          (const __attribute__((address_space(1))) void*)sb,
          (__attribute__((address_space(3))) void*)((char*)&Bs[0][0] + ch*1024),
          16, 0, 0);
    }
    __syncthreads();                           // drains vmcnt -> tiles ready
    short8 af[4], bfr[4];
    #pragma unroll
    for (int mi = 0; mi < 4; mi++)
      af[mi] = *(const short8*)(const void*)&As[wm*64 + mi*16 + u][quad*8];
    #pragma unroll
    for (int ni = 0; ni < 4; ni++)
      bfr[ni] = *(const short8*)(const void*)&Bs[wn*64 + ni*16 + u][quad*8];
    #pragma unroll
    for (int mi = 0; mi < 4; mi++)
      #pragma unroll
      for (int ni = 0; ni < 4; ni++)
        acc[mi][ni] = __builtin_amdgcn_mfma_f32_16x16x32_bf16(af[mi], bfr[ni], acc[mi][ni], 0, 0, 0);
  }
  // epilogue: +bias, Gperm layout [t][blk32][jt16][g4][u16][qd4]
  #pragma unroll
  for (int mi = 0; mi < 4; mi++){
    #pragma unroll
    for (int ni = 0; ni < 4; ni++){
      long mm = m0 + wm*64 + mi*16 + quad*4;   // 4 r's = 4 consecutive b (qd 0..3)
      int n = n0 + wn*64 + ni*16 + u;
      float bv = bias[n];
      int t = (int)(mm >> 7);
      int b = (int)(mm & 127);
      int blk = b >> 2;                         // b % 4 == 0 here
      int g = n >> 8, j = n & 255, ut = j & 15, jt = j >> 4;
      long idx = ((((long)t*32 + blk)*16 + jt)*4 + g)*64 + ut*4;
      short4v pk;
      #pragma unroll
      for (int r = 0; r < 4; r++) pk[r] = (short)f2bf(acc[mi][ni][r] + bv);
      *(short4v*)(void*)(Cout + idx) = pk;
    }
  }
}

// ---------- exclusive cumsum over t, in place on E (bf16, time-major rows) ----------
__global__ __launch_bounds__(256) void k_cum200(ushort_t* __restrict__ E){
  int b = blockIdx.x;
  int c = threadIdx.x;
  if (c >= LIN_) return;
  float acc = 0.f;
  ushort_t* p = E + (long)b * LIN_ + c;      // row (t*128+b)
  const long rs = (long)B_ * LIN_;           // per-t stride
  for (int t0 = 0; t0 < T_; t0 += 16){
    float vv[16];
    #pragma unroll
    for (int i = 0; i < 16; i++) vv[i] = bf2f(p[i*rs]);
    #pragma unroll
    for (int i = 0; i < 16; i++){ p[i*rs] = f2bf(acc); acc += vv[i]; }
    p += 16*rs;
  }
}

// ---------- z = tanh((CW[t]-CW[ls])*inv + posW + wlW + b), t=0 -> 0, pad K to 224 ----------
__global__ __launch_bounds__(256) void k_z(
    const ushort_t* __restrict__ CW, const int* __restrict__ ls, const int* __restrict__ lp,
    const int* __restrict__ wid, const float* __restrict__ inv,
    const float* __restrict__ posW, const float* __restrict__ wlW,
    const float* __restrict__ fcb, ushort_t* __restrict__ zbf){
  int l = threadIdx.x;
  if (l >= LINP_) return;
  float fb = (l < LIN_) ? fcb[l] : 0.f;
  #pragma unroll
  for (int i = 0; i < 8; i++){
    int m = blockIdx.x * 8 + i;       // time-major row t*128+b
    int t = m >> 7;
    int b = m & 127;
    int ar = b * T_ + t;              // b-major aux index
    ushort_t o = 0;
    if (t != 0 && l < LIN_){
      int lsv = ls[ar];
      float x = bf2f(CW[(long)m * LIN_ + l]) - bf2f(CW[((long)lsv * B_ + b) * LIN_ + l]);
      x = x * inv[ar] + posW[lp[ar]*LIN_ + l] + wlW[wid[ar]*LIN_ + l] + fb;
      o = f2bf(ftanh(x));
    }
    zbf[(long)m * LINP_ + l] = o;
  }
}

// ---------- LSTM recurrence: 32 blocks x 1024 threads, NB=4 batches/block ----------
// Round-5 plateau form (438us): lgkm-only barrier, early dump/prefetch, interleaved
// activations. Per-step budget = 1104cyc MFMA issue (shape-invariant) + dependency
// tails; further scheduling levers measured neutral. Structural plateau.
__global__ __launch_bounds__(1024, 4) void k_rec(
    const ushort_t* __restrict__ Gperm, const char* __restrict__ whh8,
    ushort_t* __restrict__ vbf){
  int blk  = blockIdx.x;                      // 0..31: batches blk*4 .. blk*4+3
  int tid  = threadIdx.x;
  int lane = tid & 63, w = tid >> 6;          // w in [0,16): hidden j-tile
  int u = lane & 15, quad = lane >> 4;        // quad = local batch index
  __shared__ __attribute__((aligned(16))) char h8[2][16][272];   // row stride 272
  for (int i = tid; i < (int)(sizeof(h8)/4); i += 1024) ((int*)h8)[i] = 0;

  // W_hh fp8 B-fragments (MX K=128): gate g, cols w*16+u; pinned in VGPRs.
  intx8 wfx[4][2];
  #pragma unroll
  for (int g = 0; g < 4; g++){
    int grow = g*256 + w*16 + u;
    #pragma unroll
    for (int kc = 0; kc < 2; kc++){
      intx8 v = *(const intx8*)(const void*)(whh8 + (long)grow*256 + kc*128 + quad*32);
      asm volatile("" : "+v"(v));
      wfx[g][kc] = v;
    }
  }
  float c_reg = 0.f;
  floatx4 acc[4] = {};   // element 0 rebuilt each step; elements 1..3 stay 0 forever

  // Gperm[t][blk][w][g][u][qd]: lane (quad,u) reads gate g at g*64 + u*4 + quad
  const ushort_t* gp0 = Gperm + ((long)blk*16 + w)*256 + (long)u*4 + quad;
  ushort_t gb[4];
  #pragma unroll
  for (int g = 0; g < 4; g++) gb[g] = gp0[g*64];

  for (int t = 0; t < T_; t++){
    #pragma unroll
    for (int g = 0; g < 4; g++) acc[g][0] = bf2f(gb[g]);
    // lgkm-only barrier: h8 write(t-1) -> read(t) edge; vbf store + Gperm loads
    // stay in flight across the barrier (T4: never drain vmcnt in the loop).
    asm volatile("s_waitcnt lgkmcnt(0)\n\ts_barrier" ::: "memory");
    intx8 af0 = *(const intx8*)(const void*)&h8[t & 1][u][quad*32];
    intx8 af1 = *(const intx8*)(const void*)&h8[t & 1][u][128 + quad*32];
    // EARLY: coalesced vbf dump of h(t-1) (independent of MFMAs; VMEM pipe)
    if (t && w < 4){
      ushort_t* vrow = vbf + ((long)(t-1) * B_ + blk*4 + w) * 768;
      uint32 p = *(const uint32*)(const void*)&h8[t & 1][4*w][lane*4];
      float2v lo = __builtin_amdgcn_cvt_pk_f32_fp8(p, false);
      float2v hi = __builtin_amdgcn_cvt_pk_f32_fp8(p, true);
      short4v pk;
      pk[0] = (short)f2bf(lo[0]); pk[1] = (short)f2bf(lo[1]);
      pk[2] = (short)f2bf(hi[0]); pk[3] = (short)f2bf(hi[1]);
      *(short4v*)(void*)&vrow[lane*4] = pk;
    }
    // EARLY: prefetch next Gperm values (hides HBM latency under MFMAs)
    if (t + 1 < T_){
      const ushort_t* gp = gp0 + (long)(t+1)*131072;
      #pragma unroll
      for (int g = 0; g < 4; g++) gb[g] = gp[g*64];
    }
    // gates i,f
    acc[0] = __builtin_amdgcn_mfma_scale_f32_16x16x128_f8f6f4(
        af0, wfx[0][0], acc[0], 0, 0, 0, 0x7F7F7F7F, 0, 0x7F7F7F7F);
    acc[0] = __builtin_amdgcn_mfma_scale_f32_16x16x128_f8f6f4(
        af1, wfx[0][1], acc[0], 0, 0, 0, 0x7F7F7F7F, 0, 0x7F7F7F7F);
    acc[1] = __builtin_amdgcn_mfma_scale_f32_16x16x128_f8f6f4(
        af0, wfx[1][0], acc[1], 0, 0, 0, 0x7F7F7F7F, 0, 0x7F7F7F7F);
    acc[1] = __builtin_amdgcn_mfma_scale_f32_16x16x128_f8f6f4(
        af1, wfx[1][1], acc[1], 0, 0, 0, 0x7F7F7F7F, 0, 0x7F7F7F7F);
    // i,f activations co-issue on VALU while g,o MFMAs occupy the matrix pipe
    float iv = fsig (acc[0][0]);
    float fv = fsig (acc[1][0]);
    // gates g,o
    acc[2] = __builtin_amdgcn_mfma_scale_f32_16x16x128_f8f6f4(
        af0, wfx[2][0], acc[2], 0, 0, 0, 0x7F7F7F7F, 0, 0x7F7F7F7F);
    acc[2] = __builtin_amdgcn_mfma_scale_f32_16x16x128_f8f6f4(
        af1, wfx[2][1], acc[2], 0, 0, 0, 0x7F7F7F7F, 0, 0x7F7F7F7F);
    acc[3] = __builtin_amdgcn_mfma_scale_f32_16x16x128_f8f6f4(
        af0, wfx[3][0], acc[3], 0, 0, 0, 0x7F7F7F7F, 0, 0x7F7F7F7F);
    acc[3] = __builtin_amdgcn_mfma_scale_f32_16x16x128_f8f6f4(
        af1, wfx[3][1], acc[3], 0, 0, 0, 0x7F7F7F7F, 0, 0x7F7F7F7F);
    float gv = ftanh(acc[2][0]);
    float ov = fsig (acc[3][0]);
    float c  = fv * c_reg + iv * gv;
    c_reg = c;
    float h  = ov * ftanh(c);
    int p8 = __builtin_amdgcn_cvt_pk_fp8_f32(h, h, 0, false);
    h8[(t+1)&1][quad*4][w*16 + u] = (char)(p8 & 0xff);
  }
  __syncthreads();
  // final dump: h(511) lives in h8[0]
  if (w < 4){
    ushort_t* vrow = vbf + ((long)(T_-1) * B_ + blk*4 + w) * 768;
    uint32 p = *(const uint32*)(const void*)&h8[0][4*w][lane*4];
    float2v lo = __builtin_amdgcn_cvt_pk_f32_fp8(p, false);
    float2v hi = __builtin_amdgcn_cvt_pk_f32_fp8(p, true);
    short4v pk;
    pk[0] = (short)f2bf(lo[0]); pk[1] = (short)f2bf(lo[1]);
    pk[2] = (short)f2bf(hi[0]); pk[3] = (short)f2bf(hi[1]);
    *(short4v*)(void*)&vrow[lane*4] = pk;
  }
}

extern "C" void kernel_launch(void* const* d_in, const int* in_sizes, int n_in,
                              void* d_out, int out_size, void* d_ws, size_t ws_size,
                              hipStream_t stream){
  (void)in_sizes; (void)n_in; (void)out_size; (void)ws_size;
  const float* enc     = (const float*)d_in[0];
  const int*   sep     = (const int*)  d_in[1];
  const int*   pos_ids = (const int*)  d_in[2];
  const int*   len     = (const int*)  d_in[3];
  const float* pos_emb = (const float*)d_in[4];
  const float* wl_emb  = (const float*)d_in[5];
  const float* fcW     = (const float*)d_in[6];
  const float* fcb     = (const float*)d_in[7];
  const float* W_ih    = (const float*)d_in[8];
  const float* W_hh    = (const float*)d_in[9];
  const float* b_ih    = (const float*)d_in[10];
  const float* b_hh    = (const float*)d_in[11];
  const float* combW   = (const float*)d_in[12];

  char* ws = (char*)d_ws;
  int*      ls    = (int*)     (ws + OFF_LS);
  int*      lp    = (int*)     (ws + OFF_LP);
  int*      wid   = (int*)     (ws + OFF_WID);
  float*    inv   = (float*)   (ws + OFF_INV);
  float*    posW  = (float*)   (ws + OFF_POSW);
  float*    wlW   = (float*)   (ws + OFF_WLW);
  float*    biasg = (float*)   (ws + OFF_BIASG);
  char*     whh8  = (char*)    (ws + OFF_WHH);
  ushort_t* wih   = (ushort_t*)(ws + OFF_WIH);
  ushort_t* wenc  = (ushort_t*)(ws + OFF_WENC);
  ushort_t* combwb= (ushort_t*)(ws + OFF_COMBW);
  ushort_t* ecw   = (ushort_t*)(ws + OFF_ECW);
  ushort_t* zbf   = (ushort_t*)(ws + OFF_Z);
  ushort_t* gperm = (ushort_t*)(ws + OFF_GPERM);
  ushort_t* vbf   = (ushort_t*)(ws + OFF_VBF);

  k_scan<<<B_, 512, 0, stream>>>(sep, pos_ids, ls, lp, wid, inv);
  k_encbf<<<2048, 256, 0, stream>>>(enc, vbf);
  k_small<<<2530, 256, 0, stream>>>(pos_emb, wl_emb, fcW, W_ih, W_hh, b_ih, b_hh, combW,
                                    posW, wlW, biasg, whh8, wih, wenc, combwb);
  // E = enc @ Wenc^T  (rows time-major)
  k_gemm<0><<<dim3(4, BT_/64), 256, 0, stream>>>(vbf + 256, 768L, wenc, 512, LIN_, ecw, nullptr, nullptr);
  // exclusive cumsum over t (in place) -> CW
  k_cum200<<<B_, 256, 0, stream>>>(ecw);
  // z = tanh(...) (8 rows per block)
  k_z<<<BT_/8, 256, 0, stream>>>(ecw, ls, lp, wid, inv, posW, wlW, fcb, zbf);
  // Gperm = z @ W_ih^T + biases: 128x128 tile + global_load_lds (m97 structure)
  k_g128<<<dim3(8, BT_/128), 256, 0, stream>>>(zbf, wih, gperm, biasg);
  // LSTM recurrence (round-5 plateau form)
  k_rec<<<32, 1024, 0, stream>>>(gperm, whh8, vbf);
  // logits = [hs, enc] @ combine_W^T, masked, scattered to b-major output
  k_gemm<2><<<dim3(1, BT_/64), 256, 0, stream>>>(vbf, 768L, combwb, 768, SP_, d_out, nullptr, len);
}

// Round 9
// 822.984 us; speedup vs baseline: 1.2732x; 1.0593x over previous
//
#include <hip/hip_runtime.h>

typedef unsigned short ushort_t;
typedef unsigned int uint32;
typedef __attribute__((ext_vector_type(8))) short short8;
typedef __attribute__((ext_vector_type(4))) short short4v;
typedef __attribute__((ext_vector_type(4))) float floatx4;
typedef __attribute__((ext_vector_type(2))) float float2v;
typedef __attribute__((ext_vector_type(8))) int intx8;

#define B_    128
#define T_    512
#define H_    256
#define H2_   512
#define LIN_  200
#define LINP_ 224
#define G4_   1024
#define SP_   58
#define BT_   (B_*T_)

// ---------- ws layout (bytes) ----------
#define OFF_LS     0UL          // int  [B,T]      262144
#define OFF_LP     262144UL     // int  [B,T]      262144
#define OFF_WID    524288UL     // int  [B,T]      262144
#define OFF_INV    786432UL     // f32  [B,T]      262144
#define OFF_POSW   1212416UL    // f32  [32][200]   25600
#define OFF_WLW    1238016UL    // f32  [8][200]     6400
#define OFF_BIASG  1244416UL    // f32  [1024]       4096
#define OFF_WHH    1248512UL    // fp8  [1024][256] 262144
#define OFF_WIH    1772800UL    // bf16 [1024][224] 458752
#define OFF_WENC   2231552UL    // bf16 [200][512]  204800
#define OFF_COMBW  2436352UL    // bf16 [58][768]    89088
#define OFF_ECW    2525440UL    // bf16 [65536][200] time-major rows (t*128+b)
#define OFF_Z      28739840UL   // bf16 [65536][224] time-major rows
#define OFF_GPERM  58099968UL   // bf16 swizzled [512][32 blk][16 w][4 g][16 u][4 qd]
#define OFF_VBF    192317696UL  // bf16 [65536][768] time-major rows (0:256 hs, 256:768 enc)

__device__ __forceinline__ ushort_t f2bf(float x){
  uint32 u = __float_as_uint(x);
  u += 0x7fffu + ((u >> 16) & 1u);
  return (ushort_t)(u >> 16);
}
__device__ __forceinline__ float bf2f(ushort_t v){
  return __uint_as_float(((uint32)v) << 16);
}
// fast sigmoid/tanh (exp2-based __expf + v_rcp); |err| ~1e-5, way inside bf16
__device__ __forceinline__ float fsig(float x){
  return __builtin_amdgcn_rcpf(1.0f + __expf(-x));
}
__device__ __forceinline__ float ftanh(float x){
  return 1.0f - 2.0f * __builtin_amdgcn_rcpf(1.0f + __expf(2.0f * x));
}

// ---------- scan: last_sep / wordlen / last_pos, parallel Hillis-Steele ----------
__global__ __launch_bounds__(512) void k_scan(const int* __restrict__ sep, const int* __restrict__ pos_ids,
                       int* __restrict__ ls, int* __restrict__ lp,
                       int* __restrict__ wid, float* __restrict__ inv){
  int b = blockIdx.x, t = threadIdx.x;
  __shared__ int sm[512];
  int v = (sep[b*T_ + t] > 0) ? t : 0;
  sm[t] = v;
  __syncthreads();
  #pragma unroll
  for (int off = 1; off < 512; off <<= 1){
    int o = (t >= off) ? sm[t - off] : 0;
    __syncthreads();
    v = (o > v) ? o : v;
    sm[t] = v;
    __syncthreads();
  }
  int l = (t == 0) ? 0 : sm[t - 1];      // last sep strictly before t
  int wlen = t - l;
  int wsv  = (wlen < 1) ? 1 : wlen;
  ls[b*T_ + t]  = l;
  lp[b*T_ + t]  = pos_ids[b*T_ + l];
  wid[b*T_ + t] = (wsv > 7) ? 7 : wsv;
  inv[b*T_ + t] = 1.0f / (float)wsv;
}

// ---------- enc -> bf16 into vbf[t*128+b][256:768] ----------
__global__ __launch_bounds__(256) void k_encbf(const float* __restrict__ enc, ushort_t* __restrict__ vbf){
  const long total = (long)BT_ * 128;          // float4 count (65536 rows x 128)
  for (long i = (long)blockIdx.x * 256 + threadIdx.x; i < total; i += 2048L * 256){
    floatx4 v = ((const floatx4*)enc)[i];
    long row = i >> 7;                         // b*512 + t (enc layout)
    int c4 = (int)(i & 127);
    int b = (int)(row >> 9), t = (int)(row & (T_-1));
    short4v pk;
    pk[0] = (short)f2bf(v[0]); pk[1] = (short)f2bf(v[1]);
    pk[2] = (short)f2bf(v[2]); pk[3] = (short)f2bf(v[3]);
    *(short4v*)(void*)(vbf + ((long)t * B_ + b) * 768 + 256 + c4*4) = pk;
  }
}

// ---------- small precomputes / weight conversions ----------
__global__ __launch_bounds__(256) void k_small(
    const float* __restrict__ pos_emb, const float* __restrict__ wl_emb,
    const float* __restrict__ fcW, const float* __restrict__ W_ih,
    const float* __restrict__ W_hh, const float* __restrict__ b_ih,
    const float* __restrict__ b_hh, const float* __restrict__ combW,
    float* __restrict__ posW, float* __restrict__ wlW, float* __restrict__ biasg,
    char* __restrict__ whh8, ushort_t* __restrict__ wih,
    ushort_t* __restrict__ wenc, ushort_t* __restrict__ combwb){
  int idx = blockIdx.x * 256 + threadIdx.x;
  if (idx < 6400){
    int p = idx / 200, l = idx % 200;
    float s = 0.f;
    for (int d = 0; d < 50; d++) s += pos_emb[p*50 + d] * fcW[l*582 + d];
    posW[idx] = s; return;
  }
  idx -= 6400;
  if (idx < 1600){
    int w = idx / 200, l = idx % 200;
    float s = 0.f;
    for (int d = 0; d < 20; d++) s += wl_emb[w*20 + d] * fcW[l*582 + 562 + d];
    wlW[idx] = s; return;
  }
  idx -= 1600;
  if (idx < 1024){ biasg[idx] = b_ih[idx] + b_hh[idx]; return; }
  idx -= 1024;
  if (idx < 262144){
    int p8 = __builtin_amdgcn_cvt_pk_fp8_f32(W_hh[idx], W_hh[idx], 0, false);
    whh8[idx] = (char)(p8 & 0xff);
    return;
  }
  idx -= 262144;
  if (idx < 229376){
    int n = idx / 224, k = idx % 224;
    wih[idx] = (k < 200) ? f2bf(W_ih[n*200 + k]) : (ushort_t)0;
    return;
  }
  idx -= 229376;
  if (idx < 102400){
    int l = idx / 512, c = idx % 512;
    wenc[idx] = f2bf(fcW[l*582 + 50 + c]); return;
  }
  idx -= 102400;
  if (idx < 44544){ combwb[idx] = f2bf(combW[idx]); return; }
}

// ---------- generic 64x64 bf16 MFMA GEMM (kept for gemm<2>, ragged N) ----------
template<int EPI>
__global__ __launch_bounds__(256) void k_gemm(
    const ushort_t* __restrict__ A, long lda,
    const ushort_t* __restrict__ Bm, int K, int Nvalid,
    void* __restrict__ Cout, const float* __restrict__ bias, const int* __restrict__ len){
  __shared__ __attribute__((aligned(16))) ushort_t As[64][48];
  __shared__ __attribute__((aligned(16))) ushort_t Bs[64][48];
  int tid  = threadIdx.x;
  int lane = tid & 63, wave = tid >> 6;
  int u = lane & 15, quad = lane >> 4;
  int mh = wave >> 1, nh = wave & 1;
  long m0 = (long)blockIdx.y * 64;
  int  n0 = blockIdx.x * 64;
  int lrow = tid >> 2;
  int lcol = (tid & 3) * 8;
  const ushort_t* Arow = A + (m0 + lrow) * lda + lcol;
  bool bvalid = (n0 + lrow) < Nvalid;
  const ushort_t* Brow = Bm + (long)(n0 + lrow) * K + lcol;
  floatx4 acc[2][2] = {};
  for (int k = 0; k < K; k += 32){
    short8 av = *(const short8*)(const void*)(Arow + k);
    short8 bv = {0,0,0,0,0,0,0,0};
    if (bvalid) bv = *(const short8*)(const void*)(Brow + k);
    __syncthreads();
    *(short8*)(void*)&As[lrow][lcol] = av;
    *(short8*)(void*)&Bs[lrow][lcol] = bv;
    __syncthreads();
    short8 a0 = *(const short8*)(const void*)&As[mh*32 + u][quad*8];
    short8 a1 = *(const short8*)(const void*)&As[mh*32 + 16 + u][quad*8];
    short8 b0 = *(const short8*)(const void*)&Bs[nh*32 + u][quad*8];
    short8 b1 = *(const short8*)(const void*)&Bs[nh*32 + 16 + u][quad*8];
    acc[0][0] = __builtin_amdgcn_mfma_f32_16x16x32_bf16(a0, b0, acc[0][0], 0, 0, 0);
    acc[0][1] = __builtin_amdgcn_mfma_f32_16x16x32_bf16(a0, b1, acc[0][1], 0, 0, 0);
    acc[1][0] = __builtin_amdgcn_mfma_f32_16x16x32_bf16(a1, b0, acc[1][0], 0, 0, 0);
    acc[1][1] = __builtin_amdgcn_mfma_f32_16x16x32_bf16(a1, b1, acc[1][1], 0, 0, 0);
  }
  for (int mi = 0; mi < 2; mi++){
    for (int ni = 0; ni < 2; ni++){
      for (int r = 0; r < 4; r++){
        long m = m0 + mh*32 + mi*16 + quad*4 + r;
        int  n = n0 + nh*32 + ni*16 + u;
        float v = acc[mi][ni][r];
        if (EPI == 0){
          if (n < Nvalid) ((ushort_t*)Cout)[m * Nvalid + n] = f2bf(v);
        } else {
          if (n < Nvalid){
            int t = (int)(m >> 7); int b = (int)(m & 127);
            float o = (t < len[b]) ? v : 0.0f;
            if (t == 0 && n == 0) o = -1e30f;
            ((float*)Cout)[((long)b * T_ + t) * SP_ + n] = o;
          }
        }
      }
    }
  }
}

// ---------- 128x256 8-wave double-buffered bf16 GEMM (mid GEMMs, short K) ----------
// T3-minimal: STAGE(buf^1) issued before compute(buf); ONE vmcnt(0)+barrier per
// K-step (vs 2 barriers + serial stage in the 64sq template). Per-barrier MFMA work
// = 32 inst/SIMD (~620cyc) vs ~300cyc overhead -> overhead amortized even at K=224.
// LDS linear [row][32] (gload_lds dst must be linear); bank conflicts on the 16-row
// b128 reads broken by XOR swizzle byte^=((row>>1)&3)<<4 applied BOTH sides (rule
// #21): source granule pre-swizzled for gload_lds, read addr swizzled identically.
// EPI 0: bf16 out [m][Nvalid] (N=200 ragged: B rows 200..255 read in-bounds garbage
// that only feeds never-stored output cols). EPI 1: +bias, Gperm layout (formula
// harness-verified in round 8's k_g128).
template<int EPI>
__global__ __launch_bounds__(512, 2) void k_big(
    const ushort_t* __restrict__ A, long lda,
    const ushort_t* __restrict__ Bm, int K, int Nvalid,
    void* __restrict__ Cout, const float* __restrict__ bias){
  __shared__ __attribute__((aligned(16))) ushort_t As[2][128][32];
  __shared__ __attribute__((aligned(16))) ushort_t Bs[2][256][32];
  int tid  = threadIdx.x;
  int lane = tid & 63, w = tid >> 6;          // 8 waves
  int u = lane & 15, quad = lane >> 4;
  int wm = w >> 2, wn = w & 3;                // 2x4 wave grid, 64x64 per wave
  long m0 = (long)blockIdx.y * 128;
  int  n0 = blockIdx.x * 256;
  // staging geometry: lane -> (row-in-chunk, physical granule); source pre-swizzle
  int sr = lane >> 2;
  int gp = lane & 3;
  int gl = gp ^ ((sr >> 1) & 3);              // logical granule this lane must fetch
  int arow = w*16 + sr;                        // A: wave stages 16 rows
  const ushort_t* asrc = A + (m0 + arow) * lda + gl*8;
  int brow = w*32 + sr;                        // B: wave stages 32 rows (2 insts)
  const ushort_t* bsrc0 = Bm + (long)(n0 + brow) * K + gl*8;
  const ushort_t* bsrc1 = Bm + (long)(n0 + brow + 16) * K + gl*8;
  floatx4 acc[4][4] = {};

#define STAGEK(buf, kk) do{ \
    __builtin_amdgcn_global_load_lds( \
        (const __attribute__((address_space(1))) void*)(asrc + (kk)), \
        (__attribute__((address_space(3))) void*)((char*)&As[buf][0][0] + w*1024), 16, 0, 0); \
    __builtin_amdgcn_global_load_lds( \
        (const __attribute__((address_space(1))) void*)(bsrc0 + (kk)), \
        (__attribute__((address_space(3))) void*)((char*)&Bs[buf][0][0] + w*2048), 16, 0, 0); \
    __builtin_amdgcn_global_load_lds( \
        (const __attribute__((address_space(1))) void*)(bsrc1 + (kk)), \
        (__attribute__((address_space(3))) void*)((char*)&Bs[buf][0][0] + w*2048 + 1024), 16, 0, 0); \
  }while(0)

  STAGEK(0, 0);
  asm volatile("s_waitcnt vmcnt(0)\n\ts_barrier" ::: "memory");
  int nk = K >> 5;
  int cur = 0;
  for (int ks = 0; ks < nk; ks++){
    if (ks + 1 < nk) STAGEK(cur ^ 1, (ks + 1) << 5);
    short8 af[4], bfv[4];
    #pragma unroll
    for (int mi = 0; mi < 4; mi++){
      int row = wm*64 + mi*16 + u;
      int off = (row*64 + quad*16) ^ (((row >> 1) & 3) << 4);
      af[mi] = *(const short8*)(const void*)((const char*)&As[cur][0][0] + off);
    }
    #pragma unroll
    for (int ni = 0; ni < 4; ni++){
      int row = wn*64 + ni*16 + u;
      int off = (row*64 + quad*16) ^ (((row >> 1) & 3) << 4);
      bfv[ni] = *(const short8*)(const void*)((const char*)&Bs[cur][0][0] + off);
    }
    #pragma unroll
    for (int mi = 0; mi < 4; mi++)
      #pragma unroll
      for (int ni = 0; ni < 4; ni++)
        acc[mi][ni] = __builtin_amdgcn_mfma_f32_16x16x32_bf16(af[mi], bfv[ni], acc[mi][ni], 0, 0, 0);
    asm volatile("s_waitcnt vmcnt(0)\n\ts_barrier" ::: "memory");
    cur ^= 1;
  }
#undef STAGEK

  if (EPI == 1){
    #pragma unroll
    for (int mi = 0; mi < 4; mi++){
      #pragma unroll
      for (int ni = 0; ni < 4; ni++){
        long mm = m0 + wm*64 + mi*16 + quad*4;   // 4 r's = 4 consecutive b (qd 0..3)
        int n = n0 + wn*64 + ni*16 + u;
        float bv = bias[n];
        int t = (int)(mm >> 7);
        int b = (int)(mm & 127);
        int blk = b >> 2;                         // b % 4 == 0 here
        int g = n >> 8, j = n & 255, ut = j & 15, jt = j >> 4;
        long idx = ((((long)t*32 + blk)*16 + jt)*4 + g)*64 + ut*4;
        short4v pk;
        #pragma unroll
        for (int r = 0; r < 4; r++) pk[r] = (short)f2bf(acc[mi][ni][r] + bv);
        *(short4v*)(void*)((ushort_t*)Cout + idx) = pk;
      }
    }
  } else {
    for (int mi = 0; mi < 4; mi++){
      for (int ni = 0; ni < 4; ni++){
        int n = n0 + wn*64 + ni*16 + u;
        if (n < Nvalid){
          #pragma unroll
          for (int r = 0; r < 4; r++){
            long m = m0 + wm*64 + mi*16 + quad*4 + r;
            ((ushort_t*)Cout)[m * Nvalid + n] = f2bf(acc[mi][ni][r]);
          }
        }
      }
    }
  }
}

// ---------- exclusive cumsum over t, in place on E (bf16, time-major rows) ----------
__global__ __launch_bounds__(256) void k_cum200(ushort_t* __restrict__ E){
  int b = blockIdx.x;
  int c = threadIdx.x;
  if (c >= LIN_) return;
  float acc = 0.f;
  ushort_t* p = E + (long)b * LIN_ + c;      // row (t*128+b)
  const long rs = (long)B_ * LIN_;           // per-t stride
  for (int t0 = 0; t0 < T_; t0 += 16){
    float vv[16];
    #pragma unroll
    for (int i = 0; i < 16; i++) vv[i] = bf2f(p[i*rs]);
    #pragma unroll
    for (int i = 0; i < 16; i++){ p[i*rs] = f2bf(acc); acc += vv[i]; }
    p += 16*rs;
  }
}

// ---------- z = tanh((CW[t]-CW[ls])*inv + posW + wlW + b), t=0 -> 0, pad K to 224 ----------
__global__ __launch_bounds__(256) void k_z(
    const ushort_t* __restrict__ CW, const int* __restrict__ ls, const int* __restrict__ lp,
    const int* __restrict__ wid, const float* __restrict__ inv,
    const float* __restrict__ posW, const float* __restrict__ wlW,
    const float* __restrict__ fcb, ushort_t* __restrict__ zbf){
  int l = threadIdx.x;
  if (l >= LINP_) return;
  float fb = (l < LIN_) ? fcb[l] : 0.f;
  #pragma unroll
  for (int i = 0; i < 8; i++){
    int m = blockIdx.x * 8 + i;       // time-major row t*128+b
    int t = m >> 7;
    int b = m & 127;
    int ar = b * T_ + t;              // b-major aux index
    ushort_t o = 0;
    if (t != 0 && l < LIN_){
      int lsv = ls[ar];
      float x = bf2f(CW[(long)m * LIN_ + l]) - bf2f(CW[((long)lsv * B_ + b) * LIN_ + l]);
      x = x * inv[ar] + posW[lp[ar]*LIN_ + l] + wlW[wid[ar]*LIN_ + l] + fb;
      o = f2bf(ftanh(x));
    }
    zbf[(long)m * LINP_ + l] = o;
  }
}

// ---------- LSTM recurrence: 32 blocks x 1024 threads, NB=4 batches/block ----------
// Round-5 plateau form (438us): lgkm-only barrier, early dump/prefetch, interleaved
// activations. Per-step budget = 1104cyc MFMA issue (shape-invariant) + dependency
// tails; further scheduling levers measured neutral. Structural plateau.
__global__ __launch_bounds__(1024, 4) void k_rec(
    const ushort_t* __restrict__ Gperm, const char* __restrict__ whh8,
    ushort_t* __restrict__ vbf){
  int blk  = blockIdx.x;                      // 0..31: batches blk*4 .. blk*4+3
  int tid  = threadIdx.x;
  int lane = tid & 63, w = tid >> 6;          // w in [0,16): hidden j-tile
  int u = lane & 15, quad = lane >> 4;        // quad = local batch index
  __shared__ __attribute__((aligned(16))) char h8[2][16][272];   // row stride 272
  for (int i = tid; i < (int)(sizeof(h8)/4); i += 1024) ((int*)h8)[i] = 0;

  // W_hh fp8 B-fragments (MX K=128): gate g, cols w*16+u; pinned in VGPRs.
  intx8 wfx[4][2];
  #pragma unroll
  for (int g = 0; g < 4; g++){
    int grow = g*256 + w*16 + u;
    #pragma unroll
    for (int kc = 0; kc < 2; kc++){
      intx8 v = *(const intx8*)(const void*)(whh8 + (long)grow*256 + kc*128 + quad*32);
      asm volatile("" : "+v"(v));
      wfx[g][kc] = v;
    }
  }
  float c_reg = 0.f;
  floatx4 acc[4] = {};   // element 0 rebuilt each step; elements 1..3 stay 0 forever

  // Gperm[t][blk][w][g][u][qd]: lane (quad,u) reads gate g at g*64 + u*4 + quad
  const ushort_t* gp0 = Gperm + ((long)blk*16 + w)*256 + (long)u*4 + quad;
  ushort_t gb[4];
  #pragma unroll
  for (int g = 0; g < 4; g++) gb[g] = gp0[g*64];

  for (int t = 0; t < T_; t++){
    #pragma unroll
    for (int g = 0; g < 4; g++) acc[g][0] = bf2f(gb[g]);
    // lgkm-only barrier: h8 write(t-1) -> read(t) edge; vbf store + Gperm loads
    // stay in flight across the barrier (T4: never drain vmcnt in the loop).
    asm volatile("s_waitcnt lgkmcnt(0)\n\ts_barrier" ::: "memory");
    intx8 af0 = *(const intx8*)(const void*)&h8[t & 1][u][quad*32];
    intx8 af1 = *(const intx8*)(const void*)&h8[t & 1][u][128 + quad*32];
    // EARLY: coalesced vbf dump of h(t-1) (independent of MFMAs; VMEM pipe)
    if (t && w < 4){
      ushort_t* vrow = vbf + ((long)(t-1) * B_ + blk*4 + w) * 768;
      uint32 p = *(const uint32*)(const void*)&h8[t & 1][4*w][lane*4];
      float2v lo = __builtin_amdgcn_cvt_pk_f32_fp8(p, false);
      float2v hi = __builtin_amdgcn_cvt_pk_f32_fp8(p, true);
      short4v pk;
      pk[0] = (short)f2bf(lo[0]); pk[1] = (short)f2bf(lo[1]);
      pk[2] = (short)f2bf(hi[0]); pk[3] = (short)f2bf(hi[1]);
      *(short4v*)(void*)&vrow[lane*4] = pk;
    }
    // EARLY: prefetch next Gperm values (hides HBM latency under MFMAs)
    if (t + 1 < T_){
      const ushort_t* gp = gp0 + (long)(t+1)*131072;
      #pragma unroll
      for (int g = 0; g < 4; g++) gb[g] = gp[g*64];
    }
    // gates i,f
    acc[0] = __builtin_amdgcn_mfma_scale_f32_16x16x128_f8f6f4(
        af0, wfx[0][0], acc[0], 0, 0, 0, 0x7F7F7F7F, 0, 0x7F7F7F7F);
    acc[0] = __builtin_amdgcn_mfma_scale_f32_16x16x128_f8f6f4(
        af1, wfx[0][1], acc[0], 0, 0, 0, 0x7F7F7F7F, 0, 0x7F7F7F7F);
    acc[1] = __builtin_amdgcn_mfma_scale_f32_16x16x128_f8f6f4(
        af0, wfx[1][0], acc[1], 0, 0, 0, 0x7F7F7F7F, 0, 0x7F7F7F7F);
    acc[1] = __builtin_amdgcn_mfma_scale_f32_16x16x128_f8f6f4(
        af1, wfx[1][1], acc[1], 0, 0, 0, 0x7F7F7F7F, 0, 0x7F7F7F7F);
    // i,f activations co-issue on VALU while g,o MFMAs occupy the matrix pipe
    float iv = fsig (acc[0][0]);
    float fv = fsig (acc[1][0]);
    // gates g,o
    acc[2] = __builtin_amdgcn_mfma_scale_f32_16x16x128_f8f6f4(
        af0, wfx[2][0], acc[2], 0, 0, 0, 0x7F7F7F7F, 0, 0x7F7F7F7F);
    acc[2] = __builtin_amdgcn_mfma_scale_f32_16x16x128_f8f6f4(
        af1, wfx[2][1], acc[2], 0, 0, 0, 0x7F7F7F7F, 0, 0x7F7F7F7F);
    acc[3] = __builtin_amdgcn_mfma_scale_f32_16x16x128_f8f6f4(
        af0, wfx[3][0], acc[3], 0, 0, 0, 0x7F7F7F7F, 0, 0x7F7F7F7F);
    acc[3] = __builtin_amdgcn_mfma_scale_f32_16x16x128_f8f6f4(
        af1, wfx[3][1], acc[3], 0, 0, 0, 0x7F7F7F7F, 0, 0x7F7F7F7F);
    float gv = ftanh(acc[2][0]);
    float ov = fsig (acc[3][0]);
    float c  = fv * c_reg + iv * gv;
    c_reg = c;
    float h  = ov * ftanh(c);
    int p8 = __builtin_amdgcn_cvt_pk_fp8_f32(h, h, 0, false);
    h8[(t+1)&1][quad*4][w*16 + u] = (char)(p8 & 0xff);
  }
  __syncthreads();
  // final dump: h(511) lives in h8[0]
  if (w < 4){
    ushort_t* vrow = vbf + ((long)(T_-1) * B_ + blk*4 + w) * 768;
    uint32 p = *(const uint32*)(const void*)&h8[0][4*w][lane*4];
    float2v lo = __builtin_amdgcn_cvt_pk_f32_fp8(p, false);
    float2v hi = __builtin_amdgcn_cvt_pk_f32_fp8(p, true);
    short4v pk;
    pk[0] = (short)f2bf(lo[0]); pk[1] = (short)f2bf(lo[1]);
    pk[2] = (short)f2bf(hi[0]); pk[3] = (short)f2bf(hi[1]);
    *(short4v*)(void*)&vrow[lane*4] = pk;
  }
}

extern "C" void kernel_launch(void* const* d_in, const int* in_sizes, int n_in,
                              void* d_out, int out_size, void* d_ws, size_t ws_size,
                              hipStream_t stream){
  (void)in_sizes; (void)n_in; (void)out_size; (void)ws_size;
  const float* enc     = (const float*)d_in[0];
  const int*   sep     = (const int*)  d_in[1];
  const int*   pos_ids = (const int*)  d_in[2];
  const int*   len     = (const int*)  d_in[3];
  const float* pos_emb = (const float*)d_in[4];
  const float* wl_emb  = (const float*)d_in[5];
  const float* fcW     = (const float*)d_in[6];
  const float* fcb     = (const float*)d_in[7];
  const float* W_ih    = (const float*)d_in[8];
  const float* W_hh    = (const float*)d_in[9];
  const float* b_ih    = (const float*)d_in[10];
  const float* b_hh    = (const float*)d_in[11];
  const float* combW   = (const float*)d_in[12];

  char* ws = (char*)d_ws;
  int*      ls    = (int*)     (ws + OFF_LS);
  int*      lp    = (int*)     (ws + OFF_LP);
  int*      wid   = (int*)     (ws + OFF_WID);
  float*    inv   = (float*)   (ws + OFF_INV);
  float*    posW  = (float*)   (ws + OFF_POSW);
  float*    wlW   = (float*)   (ws + OFF_WLW);
  float*    biasg = (float*)   (ws + OFF_BIASG);
  char*     whh8  = (char*)    (ws + OFF_WHH);
  ushort_t* wih   = (ushort_t*)(ws + OFF_WIH);
  ushort_t* wenc  = (ushort_t*)(ws + OFF_WENC);
  ushort_t* combwb= (ushort_t*)(ws + OFF_COMBW);
  ushort_t* ecw   = (ushort_t*)(ws + OFF_ECW);
  ushort_t* zbf   = (ushort_t*)(ws + OFF_Z);
  ushort_t* gperm = (ushort_t*)(ws + OFF_GPERM);
  ushort_t* vbf   = (ushort_t*)(ws + OFF_VBF);

  k_scan<<<B_, 512, 0, stream>>>(sep, pos_ids, ls, lp, wid, inv);
  k_encbf<<<2048, 256, 0, stream>>>(enc, vbf);
  k_small<<<2530, 256, 0, stream>>>(pos_emb, wl_emb, fcW, W_ih, W_hh, b_ih, b_hh, combW,
                                    posW, wlW, biasg, whh8, wih, wenc, combwb);
  // E = enc @ Wenc^T  (128x256 dbuf tile; N=200 in one 256 tile)
  k_big<0><<<dim3(1, BT_/128), 512, 0, stream>>>(vbf + 256, 768L, wenc, 512, LIN_, ecw, nullptr);
  // exclusive cumsum over t (in place) -> CW
  k_cum200<<<B_, 256, 0, stream>>>(ecw);
  // z = tanh(...) (8 rows per block)
  k_z<<<BT_/8, 256, 0, stream>>>(ecw, ls, lp, wid, inv, posW, wlW, fcb, zbf);
  // Gperm = z @ W_ih^T + biases (128x256 dbuf tile, Gperm-swizzled epilogue)
  k_big<1><<<dim3(4, BT_/128), 512, 0, stream>>>(zbf, (long)LINP_, wih, LINP_, G4_, gperm, biasg);
  // LSTM recurrence (round-5 plateau form)
  k_rec<<<32, 1024, 0, stream>>>(gperm, whh8, vbf);
  // logits = [hs, enc] @ combine_W^T, masked, scattered to b-major output
  k_gemm<1><<<dim3(1, BT_/64), 256, 0, stream>>>(vbf, 768L, combwb, 768, SP_, d_out, nullptr, len);
}